// Round 1
// baseline (946.775 us; speedup 1.0000x reference)
//
#include <hip/hip_runtime.h>
#include <math.h>

#define OBSD 3584
#define NEGC -9e15f

__device__ __forceinline__ float elu_f(float x) {
    return x > 0.f ? x : (__expf(x) - 1.f);
}

// LDS region map (floats, total 16384 = 64 KB):
//     0..2048   adj                       [whole kernel]
//  2048..2560   drone -> t_t -> cp/stage  [phased]
//  2560..3584   dockT                     [until heads done]
//  3584..3712   aw (dr 0..63, dk 64..127) [until P3]
//  3712..3840   src[4][32]                [until heads done]
//  3840..4096   dst[4][64]                [until heads done]
//  2048..4096   ws2 weight-stage chunks   [q/k phases]
//  4096..12288  hk_t[k][64] -> k_t[k2][64]
// 12288..14336  wdm / per-head Wdock stage
// 12288..16384  hd_t[k][32] -> q_t[k2][32]
// 14336..16384  attn[32][64]              [per head]

extern "C" __global__ __launch_bounds__(256, 2)
void gat_fused(const float* __restrict__ obs,
               const float* __restrict__ W_drone,
               const float* __restrict__ W_dock,
               const float* __restrict__ a_src,
               const float* __restrict__ a_dst,
               const float* __restrict__ Wc1,
               const float* __restrict__ bc1,
               const float* __restrict__ Wc2,
               const float* __restrict__ bc2,
               const float* __restrict__ Wad,
               const float* __restrict__ bad,
               const float* __restrict__ Wak,
               const float* __restrict__ bak,
               float* __restrict__ out_values,
               float* __restrict__ out_logits)
{
    __shared__ float s[16384];
    const int t = threadIdx.x;
    const int b = blockIdx.x;
    const float* obsrow = obs + (size_t)b * OBSD;

    // ---- P0: load obs row: drone (linear), dock (transposed), adj (linear)
    #pragma unroll
    for (int i = 0; i < 4; ++i) {
        int q4 = t + 256 * i;
        if (q4 < 896) {
            float4 v = ((const float4*)obsrow)[q4];
            int e0 = q4 * 4;
            if (e0 < 512) {
                *(float4*)&s[2048 + e0] = v;                  // drone[n][f]
            } else if (e0 < 1536) {
                int e = e0 - 512;
                float vv[4] = {v.x, v.y, v.z, v.w};
                #pragma unroll
                for (int u = 0; u < 4; ++u) {                 // dockT[f][m]
                    int m = (e + u) >> 4, f = (e + u) & 15;
                    s[2560 + f * 64 + m] = vv[u];
                }
            } else {
                *(float4*)&s[0 + (e0 - 1536)] = v;            // adj[n][m]
            }
        }
    }
    // ---- P1: aw vectors: aw_dr[h][f] = W_drone[h,f,:]·a_src[h,:] (dock analog)
    if (t < 64) {
        int h = t >> 4, f = t & 15;
        const float* wrow = W_drone + h * 2048 + f * 128;
        const float* arow = a_src + h * 128;
        float acc = 0.f;
        for (int k = 0; k < 128; ++k) acc += wrow[k] * arow[k];
        s[3584 + t] = acc;
    } else if (t < 128) {
        int tt = t - 64;
        int h = tt >> 4, f = tt & 15;
        const float* wrow = W_dock + h * 2048 + f * 128;
        const float* arow = a_dst + h * 128;
        float acc = 0.f;
        for (int k = 0; k < 128; ++k) acc += wrow[k] * arow[k];
        s[3648 + tt] = acc;
    }
    // ---- P2: wdm[f][k] = 0.25 * sum_h W_dock[h][f][k]
    #pragma unroll
    for (int i = 0; i < 8; ++i) {
        int e = t + 256 * i;
        s[12288 + e] = 0.25f * (W_dock[e] + W_dock[2048 + e] + W_dock[4096 + e] + W_dock[6144 + e]);
    }
    __syncthreads();

    // ---- P3: additive-attention pre-scores
    if (t < 128) {
        int h = t >> 5, n = t & 31;
        float acc = 0.f;
        #pragma unroll
        for (int f = 0; f < 16; ++f) acc += s[2048 + n * 16 + f] * s[3584 + h * 16 + f];
        s[3712 + t] = acc;                                    // src[h][n]
    }
    {
        int h = t >> 6, m = t & 63;
        float acc = 0.f;
        #pragma unroll
        for (int f = 0; f < 16; ++f) acc += s[2560 + f * 64 + m] * s[3648 + h * 16 + f];
        s[3840 + t] = acc;                                    // dst[h][m]
    }
    __syncthreads();

    // ---- P4: h_dock -> hk_t[k][m] = elu(dock @ wdm), tile 8m x 4k per thread
    {
        int m0 = (t >> 5) * 8, k0 = (t & 31) * 4;
        float acc[8][4];
        #pragma unroll
        for (int a = 0; a < 8; ++a)
            #pragma unroll
            for (int c = 0; c < 4; ++c) acc[a][c] = 0.f;
        #pragma unroll
        for (int f = 0; f < 16; ++f) {
            float4 d0 = *(const float4*)&s[2560 + f * 64 + m0];
            float4 d1 = *(const float4*)&s[2560 + f * 64 + m0 + 4];
            float4 w  = *(const float4*)&s[12288 + f * 128 + k0];
            float dm[8] = {d0.x, d0.y, d0.z, d0.w, d1.x, d1.y, d1.z, d1.w};
            float wk[4] = {w.x, w.y, w.z, w.w};
            #pragma unroll
            for (int a = 0; a < 8; ++a)
                #pragma unroll
                for (int c = 0; c < 4; ++c) acc[a][c] += dm[a] * wk[c];
        }
        #pragma unroll
        for (int a = 0; a < 8; ++a)
            #pragma unroll
            for (int c = 0; c < 4; ++c)
                s[4096 + (k0 + c) * 64 + m0 + a] = elu_f(acc[a][c]);
    }

    // ---- P5: head loop; h_drone accumulated in registers (4n x 4k per thread)
    const int n0h = (t >> 5) * 4, k0h = (t & 31) * 4;
    float hacc[4][4];
    #pragma unroll
    for (int a = 0; a < 4; ++a)
        #pragma unroll
        for (int c = 0; c < 4; ++c) hacc[a][c] = 0.f;

    for (int h = 0; h < 4; ++h) {
        __syncthreads();   // protects wdm/wstage + attn + t_t reuse
        // P5a: masked softmax attention row-wise (8 lanes per row) + stage Wdock[h]
        {
            int n = t >> 3, j = t & 7;
            float sv = s[3712 + h * 32 + n];
            float e8[8];
            float pmax = -INFINITY;
            #pragma unroll
            for (int c = 0; c < 8; ++c) {
                int m = j * 8 + c;
                float e = sv + s[3840 + h * 64 + m];
                e = e > 0.f ? e : 0.2f * e;                   // leaky relu
                e = (s[n * 64 + m] > 0.f) ? e : NEGC;         // adj mask
                e8[c] = e;
                pmax = fmaxf(pmax, e);
            }
            #pragma unroll
            for (int off = 1; off < 8; off <<= 1)
                pmax = fmaxf(pmax, __shfl_xor(pmax, off, 8));
            float psum = 0.f;
            #pragma unroll
            for (int c = 0; c < 8; ++c) {
                e8[c] = __expf(e8[c] - pmax);
                psum += e8[c];
            }
            #pragma unroll
            for (int off = 1; off < 8; off <<= 1)
                psum += __shfl_xor(psum, off, 8);
            float rinv = 1.f / psum;
            #pragma unroll
            for (int c = 0; c < 8; ++c)
                s[14336 + n * 64 + j * 8 + c] = e8[c] * rinv;
        }
        #pragma unroll
        for (int i = 0; i < 8; ++i) {                         // stage Wdock[h]
            int e = t + 256 * i;
            s[12288 + e] = W_dock[h * 2048 + e];
        }
        __syncthreads();
        // P5b: t_h = attn @ dock  -> t_t[f][n]
        {
            int n = t >> 3, f0 = (t & 7) * 2;
            float a0 = 0.f, a1 = 0.f;
            #pragma unroll
            for (int qd = 0; qd < 16; ++qd) {
                float4 av  = *(const float4*)&s[14336 + n * 64 + qd * 4];
                float4 dv0 = *(const float4*)&s[2560 + f0 * 64 + qd * 4];
                float4 dv1 = *(const float4*)&s[2560 + (f0 + 1) * 64 + qd * 4];
                a0 += av.x * dv0.x + av.y * dv0.y + av.z * dv0.z + av.w * dv0.w;
                a1 += av.x * dv1.x + av.y * dv1.y + av.z * dv1.z + av.w * dv1.w;
            }
            s[2048 + f0 * 32 + n] = a0;
            s[2048 + (f0 + 1) * 32 + n] = a1;
        }
        __syncthreads();
        // P5c: hacc += t_h @ Wdock[h]
        #pragma unroll
        for (int f = 0; f < 16; ++f) {
            float4 t4 = *(const float4*)&s[2048 + f * 32 + n0h];
            float4 w4 = *(const float4*)&s[12288 + f * 128 + k0h];
            float ta[4] = {t4.x, t4.y, t4.z, t4.w};
            float wa[4] = {w4.x, w4.y, w4.z, w4.w};
            #pragma unroll
            for (int a = 0; a < 4; ++a)
                #pragma unroll
                for (int c = 0; c < 4; ++c) hacc[a][c] += ta[a] * wa[c];
        }
    }
    __syncthreads();
    // write hd_t[k][n] = elu(hacc / 4)
    #pragma unroll
    for (int a = 0; a < 4; ++a)
        #pragma unroll
        for (int c = 0; c < 4; ++c)
            s[12288 + (k0h + c) * 32 + n0h + a] = elu_f(hacc[a][c] * 0.25f);
    __syncthreads();

    // ---- P6: critic. partial_j over a quarter of the 4096-dim dot
    {
        int j = t & 63, p = t >> 6;
        float partial = 0.f;
        for (int e4 = p * 256; e4 < p * 256 + 256; ++e4) {
            float4 h4 = *(const float4*)&s[12288 + e4 * 4];
            int base = e4 * 4;
            int k = base >> 5;
            int n0 = base & 31;
            float w0 = Wc1[((n0 + 0) * 128 + k) * 64 + j];
            float w1 = Wc1[((n0 + 1) * 128 + k) * 64 + j];
            float w2 = Wc1[((n0 + 2) * 128 + k) * 64 + j];
            float w3 = Wc1[((n0 + 3) * 128 + k) * 64 + j];
            partial += h4.x * w0 + h4.y * w1 + h4.z * w2 + h4.w * w3;
        }
        s[2048 + t] = partial;
    }
    __syncthreads();
    if (t < 64) {
        float hj = s[2048 + t] + s[2112 + t] + s[2176 + t] + s[2240 + t] + bc1[t];
        hj = fmaxf(hj, 0.f);
        float v = hj * Wc2[t];
        #pragma unroll
        for (int off = 32; off >= 1; off >>= 1) v += __shfl_xor(v, off, 64);
        if (t == 0) out_values[b] = v + bc2[0];
    }
    __syncthreads();

    // ---- P7: q = hd @ Wad + bad  -> q_t[k2][n] (overwrites hd_t)
    {
        float qacc[4][4];
        #pragma unroll
        for (int a = 0; a < 4; ++a)
            #pragma unroll
            for (int c = 0; c < 4; ++c) qacc[a][c] = 0.f;
        for (int cc = 0; cc < 8; ++cc) {
            #pragma unroll
            for (int i = 0; i < 8; ++i) {
                int e = t + 256 * i;
                s[2048 + e] = Wad[cc * 2048 + e];
            }
            __syncthreads();
            #pragma unroll
            for (int kkl = 0; kkl < 16; ++kkl) {
                int kk = cc * 16 + kkl;
                float4 h4 = *(const float4*)&s[12288 + kk * 32 + n0h];
                float4 w4 = *(const float4*)&s[2048 + kkl * 128 + k0h];
                float ha[4] = {h4.x, h4.y, h4.z, h4.w};
                float wa[4] = {w4.x, w4.y, w4.z, w4.w};
                #pragma unroll
                for (int a = 0; a < 4; ++a)
                    #pragma unroll
                    for (int c = 0; c < 4; ++c) qacc[a][c] += ha[a] * wa[c];
            }
            __syncthreads();
        }
        float4 bd = *(const float4*)&bad[k0h];
        float bdv[4] = {bd.x, bd.y, bd.z, bd.w};
        #pragma unroll
        for (int a = 0; a < 4; ++a)
            #pragma unroll
            for (int c = 0; c < 4; ++c)
                s[12288 + (k0h + c) * 32 + n0h + a] = qacc[a][c] + bdv[c];
    }
    __syncthreads();

    // ---- P8: k = h_dock @ Wak + bak -> k_t[k2][m] (overwrites hk_t)
    {
        int m0k = (t >> 4) * 4, k20 = (t & 15) * 8;
        float kacc[4][8];
        #pragma unroll
        for (int a = 0; a < 4; ++a)
            #pragma unroll
            for (int c = 0; c < 8; ++c) kacc[a][c] = 0.f;
        for (int cc = 0; cc < 8; ++cc) {
            #pragma unroll
            for (int i = 0; i < 8; ++i) {
                int e = t + 256 * i;
                s[2048 + e] = Wak[cc * 2048 + e];
            }
            __syncthreads();
            #pragma unroll
            for (int kkl = 0; kkl < 16; ++kkl) {
                int kk = cc * 16 + kkl;
                float4 h4 = *(const float4*)&s[4096 + kk * 64 + m0k];
                float4 wA = *(const float4*)&s[2048 + kkl * 128 + k20];
                float4 wB = *(const float4*)&s[2048 + kkl * 128 + k20 + 4];
                float ha[4] = {h4.x, h4.y, h4.z, h4.w};
                float wa[8] = {wA.x, wA.y, wA.z, wA.w, wB.x, wB.y, wB.z, wB.w};
                #pragma unroll
                for (int a = 0; a < 4; ++a)
                    #pragma unroll
                    for (int c = 0; c < 8; ++c) kacc[a][c] += ha[a] * wa[c];
            }
            __syncthreads();
        }
        float4 bkA = *(const float4*)&bak[k20];
        float4 bkB = *(const float4*)&bak[k20 + 4];
        float bkv[8] = {bkA.x, bkA.y, bkA.z, bkA.w, bkB.x, bkB.y, bkB.z, bkB.w};
        #pragma unroll
        for (int a = 0; a < 4; ++a)
            #pragma unroll
            for (int c = 0; c < 8; ++c)
                s[4096 + (k20 + c) * 64 + m0k + a] = kacc[a][c] + bkv[c];
    }
    __syncthreads();

    // ---- P9: scores = q @ k^T, mask with adj, write logits
    {
        int n0s = (t >> 4) * 2, m0s = (t & 15) * 4;
        float sc[2][4];
        #pragma unroll
        for (int a = 0; a < 2; ++a)
            #pragma unroll
            for (int c = 0; c < 4; ++c) sc[a][c] = 0.f;
        for (int k2 = 0; k2 < 128; ++k2) {
            float2 qv = *(const float2*)&s[12288 + k2 * 32 + n0s];
            float4 kv = *(const float4*)&s[4096 + k2 * 64 + m0s];
            sc[0][0] += qv.x * kv.x; sc[0][1] += qv.x * kv.y;
            sc[0][2] += qv.x * kv.z; sc[0][3] += qv.x * kv.w;
            sc[1][0] += qv.y * kv.x; sc[1][1] += qv.y * kv.y;
            sc[1][2] += qv.y * kv.z; sc[1][3] += qv.y * kv.w;
        }
        float* lg = out_logits + (size_t)b * 2048;
        #pragma unroll
        for (int a = 0; a < 2; ++a) {
            float4 adjv = *(const float4*)&s[(n0s + a) * 64 + m0s];
            float4 o;
            o.x = adjv.x > 0.f ? sc[a][0] : NEGC;
            o.y = adjv.y > 0.f ? sc[a][1] : NEGC;
            o.z = adjv.z > 0.f ? sc[a][2] : NEGC;
            o.w = adjv.w > 0.f ? sc[a][3] : NEGC;
            *(float4*)&lg[(n0s + a) * 64 + m0s] = o;
        }
    }
}

extern "C" void kernel_launch(void* const* d_in, const int* in_sizes, int n_in,
                              void* d_out, int out_size, void* d_ws, size_t ws_size,
                              hipStream_t stream) {
    const float* obs     = (const float*)d_in[0];
    const float* W_drone = (const float*)d_in[1];
    const float* W_dock  = (const float*)d_in[2];
    const float* a_src   = (const float*)d_in[3];
    const float* a_dst   = (const float*)d_in[4];
    const float* Wc1     = (const float*)d_in[5];
    const float* bc1     = (const float*)d_in[6];
    const float* Wc2     = (const float*)d_in[7];
    const float* bc2     = (const float*)d_in[8];
    const float* Wad     = (const float*)d_in[9];
    const float* bad     = (const float*)d_in[10];
    const float* Wak     = (const float*)d_in[11];
    const float* bak     = (const float*)d_in[12];
    float* out = (float*)d_out;

    gat_fused<<<dim3(4096), dim3(256), 0, stream>>>(
        obs, W_drone, W_dock, a_src, a_dst,
        Wc1, bc1, Wc2, bc2, Wad, bad, Wak, bak,
        out, out + 4096);
}

// Round 2
// 738.792 us; speedup vs baseline: 1.2815x; 1.2815x over previous
//
#include <hip/hip_runtime.h>
#include <math.h>

#define OBSD 3584
#define NEGC -9e15f

// ---------------- LDS map (floats, total 19968 = 79872 B, 2 blocks/CU) ------
// A_ADJ   0      adj[32][64]            (P0 -> last softmax)  } t2[128][32]
// B_OFF   2048   droneT[16][32] @2048,  aw_dr @2560, aw_dk @2624
//                then t_all[64][32]     (head loop -> P5c)    } overlaid by t2
// C_HK    4096   hk_t[128][64]          (P4 -> P9)
// D_OFF   12288  wdm[16][128] (P2->P4), then hd_t[128][32] (P5c -> P7/P6/su)
// E_DOCK  16384  dockT[16][64]          (P0 -> last P5b); critic partials,
//                then su@16384, sw@16448
// E_SRC   17408  src[4][32]
// E_DST   17536  dst[4][64]
// E_ATTN  17792  attn[32][68] (2176)    also weight-stage chunks (2048)
#define A_ADJ  0
#define B_OFF  2048
#define C_HK   4096
#define D_OFF  12288
#define E_DOCK 16384
#define E_SRC  17408
#define E_DST  17536
#define E_ATTN 17792

__device__ __forceinline__ float elu_f(float x) {
    return x > 0.f ? x : (__expf(x) - 1.f);
}

// ws float layout: M[128][128] @0, u[128] @16384, w[128] @16512, c0 @16640
__global__ __launch_bounds__(256) void setup_fold(
    const float* __restrict__ Wad, const float* __restrict__ Wak,
    const float* __restrict__ bad, const float* __restrict__ bak,
    float* __restrict__ ws)
{
    __shared__ float sa[32 * 132];
    __shared__ float sb[32 * 132];
    const int t = threadIdx.x, bi = blockIdx.x;
    if (bi < 16) {
        const int r0 = (bi >> 2) * 32, i0 = (bi & 3) * 32;
        #pragma unroll
        for (int q = 0; q < 4; ++q) {
            int e = (t + 256 * q) * 4;        // 0..4092
            int r = e >> 7, cc = e & 127;
            *(float4*)&sa[r * 132 + cc] = *(const float4*)&Wad[(r0 + r) * 128 + cc];
            *(float4*)&sb[r * 132 + cc] = *(const float4*)&Wak[(i0 + r) * 128 + cc];
        }
        __syncthreads();
        int rr = (t >> 4) * 2, ii = (t & 15) * 2;
        float a00 = 0.f, a01 = 0.f, a10 = 0.f, a11 = 0.f;
        for (int c = 0; c < 128; ++c) {
            float x0 = sa[rr * 132 + c], x1 = sa[(rr + 1) * 132 + c];
            float y0 = sb[ii * 132 + c], y1 = sb[(ii + 1) * 132 + c];
            a00 += x0 * y0; a01 += x0 * y1; a10 += x1 * y0; a11 += x1 * y1;
        }
        ws[(r0 + rr) * 128 + i0 + ii]         = a00;
        ws[(r0 + rr) * 128 + i0 + ii + 1]     = a01;
        ws[(r0 + rr + 1) * 128 + i0 + ii]     = a10;
        ws[(r0 + rr + 1) * 128 + i0 + ii + 1] = a11;
    } else {
        if (t < 128) {
            float acc = 0.f;
            for (int c = 0; c < 128; ++c) acc += Wad[t * 128 + c] * bak[c];
            ws[16384 + t] = acc;
        } else {
            int j = t - 128;
            float acc = 0.f;
            for (int c = 0; c < 128; ++c) acc += Wak[j * 128 + c] * bad[c];
            ws[16512 + j] = acc;
        }
        if (t == 0) {
            float acc = 0.f;
            for (int c = 0; c < 128; ++c) acc += bad[c] * bak[c];
            ws[16640] = acc;
        }
    }
}

extern "C" __global__ __launch_bounds__(256, 2)
void gat_fused(const float* __restrict__ obs,
               const float* __restrict__ W_drone,
               const float* __restrict__ W_dock,
               const float* __restrict__ a_src,
               const float* __restrict__ a_dst,
               const float* __restrict__ Wc1,
               const float* __restrict__ bc1,
               const float* __restrict__ Wc2,
               const float* __restrict__ bc2,
               const float* __restrict__ ws,   // M/u/w/c0
               float* __restrict__ out_values,
               float* __restrict__ out_logits)
{
    __shared__ float s[19968];
    const int t = threadIdx.x;
    const int b = blockIdx.x;
    const float* obsrow = obs + (size_t)b * OBSD;

    // ---- P0: obs row -> droneT[f][n], dockT[f][m], adj[n][m]
    #pragma unroll
    for (int i = 0; i < 4; ++i) {
        int q4 = t + 256 * i;
        if (q4 < 896) {
            float4 v = ((const float4*)obsrow)[q4];
            int e0 = q4 * 4;
            float vv[4] = {v.x, v.y, v.z, v.w};
            if (e0 < 512) {
                #pragma unroll
                for (int u2 = 0; u2 < 4; ++u2) {
                    int e = e0 + u2; int n = e >> 4, f = e & 15;
                    s[B_OFF + f * 32 + n] = vv[u2];
                }
            } else if (e0 < 1536) {
                #pragma unroll
                for (int u2 = 0; u2 < 4; ++u2) {
                    int e = e0 - 512 + u2; int m = e >> 4, f = e & 15;
                    s[E_DOCK + f * 64 + m] = vv[u2];
                }
            } else {
                *(float4*)&s[A_ADJ + (e0 - 1536)] = v;
            }
        }
    }
    // ---- P1: aw_dr[h][f] = W_drone[h,f,:]·a_src[h,:]; aw_dk analog
    if (t < 64) {
        int h = t >> 4, f = t & 15;
        const float* wrow = W_drone + h * 2048 + f * 128;
        const float* arow = a_src + h * 128;
        float acc = 0.f;
        for (int k = 0; k < 128; ++k) acc += wrow[k] * arow[k];
        s[2560 + t] = acc;
    } else if (t < 128) {
        int tt = t - 64;
        int h = tt >> 4, f = tt & 15;
        const float* wrow = W_dock + h * 2048 + f * 128;
        const float* arow = a_dst + h * 128;
        float acc = 0.f;
        for (int k = 0; k < 128; ++k) acc += wrow[k] * arow[k];
        s[2624 + tt] = acc;
    }
    // ---- P2: wdm[f][k] = mean_h W_dock
    #pragma unroll
    for (int i = 0; i < 8; ++i) {
        int e = t + 256 * i;
        s[D_OFF + e] = 0.25f * (W_dock[e] + W_dock[2048 + e] + W_dock[4096 + e] + W_dock[6144 + e]);
    }
    __syncthreads();

    // ---- P3: src[h][n], dst[h][m]
    if (t < 128) {
        int h = t >> 5, n = t & 31;
        float acc = 0.f;
        #pragma unroll
        for (int f = 0; f < 16; ++f) acc += s[B_OFF + f * 32 + n] * s[2560 + h * 16 + f];
        s[E_SRC + h * 32 + n] = acc;
    }
    {
        int h = t >> 6, m = t & 63;
        float acc = 0.f;
        #pragma unroll
        for (int f = 0; f < 16; ++f) acc += s[E_DOCK + f * 64 + m] * s[2624 + h * 16 + f];
        s[E_DST + h * 64 + m] = acc;
    }

    // ---- P4: hk_t[i][m] = elu(dock @ wdm); partition m0=8(t&7), k0=4(t>>3)
    {
        int m0 = (t & 7) * 8, k0 = (t >> 3) * 4;
        float acc[8][4];
        #pragma unroll
        for (int a = 0; a < 8; ++a)
            #pragma unroll
            for (int c = 0; c < 4; ++c) acc[a][c] = 0.f;
        #pragma unroll
        for (int f = 0; f < 16; ++f) {
            float4 d0 = *(const float4*)&s[E_DOCK + f * 64 + m0];
            float4 d1 = *(const float4*)&s[E_DOCK + f * 64 + m0 + 4];
            float4 w  = *(const float4*)&s[D_OFF + f * 128 + k0];
            float dm[8] = {d0.x, d0.y, d0.z, d0.w, d1.x, d1.y, d1.z, d1.w};
            float wk[4] = {w.x, w.y, w.z, w.w};
            #pragma unroll
            for (int a = 0; a < 8; ++a)
                #pragma unroll
                for (int c = 0; c < 4; ++c) acc[a][c] += dm[a] * wk[c];
        }
        #pragma unroll
        for (int c = 0; c < 4; ++c) {
            float4 w0 = {elu_f(acc[0][c]), elu_f(acc[1][c]), elu_f(acc[2][c]), elu_f(acc[3][c])};
            float4 w1 = {elu_f(acc[4][c]), elu_f(acc[5][c]), elu_f(acc[6][c]), elu_f(acc[7][c])};
            *(float4*)&s[C_HK + (k0 + c) * 64 + m0]     = w0;
            *(float4*)&s[C_HK + (k0 + c) * 64 + m0 + 4] = w1;
        }
    }

    // ---- P5 head loop: softmax + t_h = attn @ dock -> t_all[h*16+f][n]
    for (int h = 0; h < 4; ++h) {
        __syncthreads();
        {   // P5a: masked softmax; 8 lanes per row n
            int n = t >> 3, j = t & 7;
            float sv = s[E_SRC + h * 32 + n];
            float4 df0 = *(const float4*)&s[E_DST + h * 64 + j * 8];
            float4 df1 = *(const float4*)&s[E_DST + h * 64 + j * 8 + 4];
            float4 af0 = *(const float4*)&s[A_ADJ + n * 64 + j * 8];
            float4 af1 = *(const float4*)&s[A_ADJ + n * 64 + j * 8 + 4];
            float dstv[8] = {df0.x, df0.y, df0.z, df0.w, df1.x, df1.y, df1.z, df1.w};
            float adv[8]  = {af0.x, af0.y, af0.z, af0.w, af1.x, af1.y, af1.z, af1.w};
            float e8[8];
            float pmax = -INFINITY;
            #pragma unroll
            for (int c = 0; c < 8; ++c) {
                float e = sv + dstv[c];
                e = e > 0.f ? e : 0.2f * e;          // leaky relu
                e = adv[c] > 0.f ? e : NEGC;         // adj mask
                e8[c] = e;
                pmax = fmaxf(pmax, e);
            }
            #pragma unroll
            for (int off = 1; off < 8; off <<= 1)
                pmax = fmaxf(pmax, __shfl_xor(pmax, off, 8));
            float psum = 0.f;
            #pragma unroll
            for (int c = 0; c < 8; ++c) { e8[c] = __expf(e8[c] - pmax); psum += e8[c]; }
            #pragma unroll
            for (int off = 1; off < 8; off <<= 1)
                psum += __shfl_xor(psum, off, 8);
            float rinv = 1.f / psum;
            #pragma unroll
            for (int c = 0; c < 8; ++c)
                s[E_ATTN + n * 68 + j * 8 + c] = e8[c] * rinv;
        }
        __syncthreads();
        {   // P5b: t_h[n][f0..f0+1] = attn row n · dockT rows; n=t&31, f0=2(t>>5)
            int n = t & 31, f0 = (t >> 5) * 2;
            float a0 = 0.f, a1 = 0.f;
            #pragma unroll
            for (int qd = 0; qd < 16; ++qd) {
                float4 av = *(const float4*)&s[E_ATTN + n * 68 + qd * 4];
                float4 d0 = *(const float4*)&s[E_DOCK + f0 * 64 + qd * 4];
                float4 d1 = *(const float4*)&s[E_DOCK + (f0 + 1) * 64 + qd * 4];
                a0 += av.x * d0.x + av.y * d0.y + av.z * d0.z + av.w * d0.w;
                a1 += av.x * d1.x + av.y * d1.y + av.z * d1.z + av.w * d1.w;
            }
            s[B_OFF + (h * 16 + f0) * 32 + n]     = a0;
            s[B_OFF + (h * 16 + f0 + 1) * 32 + n] = a1;
        }
    }

    // ---- P5c: hacc = t_all(32x64) @ Wdock_flat(64x128); n0=4(t&7), k0=4(t>>3)
    const int n0h = (t & 7) * 4, k0h = (t >> 3) * 4;
    {
        float hacc[4][4];
        #pragma unroll
        for (int a = 0; a < 4; ++a)
            #pragma unroll
            for (int c = 0; c < 4; ++c) hacc[a][c] = 0.f;
        for (int cc = 0; cc < 4; ++cc) {
            __syncthreads();
            *(float4*)&s[E_ATTN + t * 8]     = *(const float4*)&W_dock[cc * 2048 + t * 8];
            *(float4*)&s[E_ATTN + t * 8 + 4] = *(const float4*)&W_dock[cc * 2048 + t * 8 + 4];
            __syncthreads();
            #pragma unroll
            for (int fl = 0; fl < 16; ++fl) {
                float4 t4 = *(const float4*)&s[B_OFF + (cc * 16 + fl) * 32 + n0h];
                float4 w4 = *(const float4*)&s[E_ATTN + fl * 128 + k0h];
                float ta[4] = {t4.x, t4.y, t4.z, t4.w};
                float wa[4] = {w4.x, w4.y, w4.z, w4.w};
                #pragma unroll
                for (int a = 0; a < 4; ++a)
                    #pragma unroll
                    for (int c = 0; c < 4; ++c) hacc[a][c] += ta[a] * wa[c];
            }
        }
        __syncthreads();
        // hd_t[k][n] = elu(hacc / 4)
        #pragma unroll
        for (int c = 0; c < 4; ++c) {
            float4 w0 = {elu_f(hacc[0][c] * 0.25f), elu_f(hacc[1][c] * 0.25f),
                         elu_f(hacc[2][c] * 0.25f), elu_f(hacc[3][c] * 0.25f)};
            *(float4*)&s[D_OFF + (k0h + c) * 32 + n0h] = w0;
        }
    }
    __syncthreads();

    // ---- P6: critic
    {
        int j = t & 63, p = t >> 6;
        float partial = 0.f;
        for (int e4 = p * 256; e4 < p * 256 + 256; ++e4) {
            float4 h4 = *(const float4*)&s[D_OFF + e4 * 4];
            int base = e4 * 4;
            int k = base >> 5;
            int n0 = base & 31;
            float w0 = Wc1[((n0 + 0) * 128 + k) * 64 + j];
            float w1 = Wc1[((n0 + 1) * 128 + k) * 64 + j];
            float w2 = Wc1[((n0 + 2) * 128 + k) * 64 + j];
            float w3 = Wc1[((n0 + 3) * 128 + k) * 64 + j];
            partial += h4.x * w0 + h4.y * w1 + h4.z * w2 + h4.w * w3;
        }
        s[E_DOCK + t] = partial;
    }
    __syncthreads();
    if (t < 64) {
        float hj = s[E_DOCK + t] + s[E_DOCK + 64 + t] + s[E_DOCK + 128 + t] + s[E_DOCK + 192 + t] + bc1[t];
        hj = fmaxf(hj, 0.f);
        float v = hj * Wc2[t];
        #pragma unroll
        for (int off = 32; off >= 1; off >>= 1) v += __shfl_xor(v, off, 64);
        if (t == 0) out_values[b] = v + bc2[0];
    }
    __syncthreads();

    // ---- P7: t2 = hd @ M -> t2_t[i][n] @ 0..4096 (overwrites adj + t_all)
    {
        float qacc[4][4];
        #pragma unroll
        for (int a = 0; a < 4; ++a)
            #pragma unroll
            for (int c = 0; c < 4; ++c) qacc[a][c] = 0.f;
        for (int cc = 0; cc < 8; ++cc) {
            __syncthreads();
            *(float4*)&s[E_ATTN + t * 8]     = *(const float4*)&ws[cc * 2048 + t * 8];
            *(float4*)&s[E_ATTN + t * 8 + 4] = *(const float4*)&ws[cc * 2048 + t * 8 + 4];
            __syncthreads();
            #pragma unroll
            for (int kkl = 0; kkl < 16; ++kkl) {
                int kk = cc * 16 + kkl;
                float4 h4 = *(const float4*)&s[D_OFF + kk * 32 + n0h];
                float4 w4 = *(const float4*)&s[E_ATTN + kkl * 128 + k0h];
                float ha[4] = {h4.x, h4.y, h4.z, h4.w};
                float wa[4] = {w4.x, w4.y, w4.z, w4.w};
                #pragma unroll
                for (int a = 0; a < 4; ++a)
                    #pragma unroll
                    for (int c = 0; c < 4; ++c) qacc[a][c] += ha[a] * wa[c];
            }
        }
        #pragma unroll
        for (int c = 0; c < 4; ++c) {
            float4 w0 = {qacc[0][c], qacc[1][c], qacc[2][c], qacc[3][c]};
            *(float4*)&s[(k0h + c) * 32 + n0h] = w0;
        }
    }
    // su[n] = hd_n · u ; sw[m] = hk_m · w
    if (t < 32) {
        float acc = 0.f;
        for (int j = 0; j < 128; ++j) acc += s[D_OFF + j * 32 + t] * ws[16384 + j];
        s[E_DOCK + t] = acc;                 // su @ 16384
    } else if (t >= 64 && t < 128) {
        int m = t - 64;
        float acc = 0.f;
        for (int i = 0; i < 128; ++i) acc += s[C_HK + i * 64 + m] * ws[16512 + i];
        s[E_DOCK + 64 + m] = acc;            // sw @ 16448
    }
    __syncthreads();

    // ---- P9: scores = t2 @ hk^T + su + sw + c0, mask via global adj re-read
    {
        int n0s = (t >> 4) * 2, m0s = (t & 15) * 4;
        float sc[2][4];
        #pragma unroll
        for (int a = 0; a < 2; ++a)
            #pragma unroll
            for (int c = 0; c < 4; ++c) sc[a][c] = 0.f;
        for (int k2 = 0; k2 < 128; ++k2) {
            float2 qv = *(const float2*)&s[k2 * 32 + n0s];
            float4 kv = *(const float4*)&s[C_HK + k2 * 64 + m0s];
            sc[0][0] += qv.x * kv.x; sc[0][1] += qv.x * kv.y;
            sc[0][2] += qv.x * kv.z; sc[0][3] += qv.x * kv.w;
            sc[1][0] += qv.y * kv.x; sc[1][1] += qv.y * kv.y;
            sc[1][2] += qv.y * kv.z; sc[1][3] += qv.y * kv.w;
        }
        float c0 = ws[16640];
        float4 swv = *(const float4*)&s[E_DOCK + 64 + m0s];
        float swa[4] = {swv.x, swv.y, swv.z, swv.w};
        float* lg = out_logits + (size_t)b * 2048;
        #pragma unroll
        for (int a = 0; a < 2; ++a) {
            float su_ = s[E_DOCK + n0s + a];
            float4 adjv = *(const float4*)&obsrow[1536 + (n0s + a) * 64 + m0s];
            float4 o;
            o.x = adjv.x > 0.f ? sc[a][0] + su_ + swa[0] + c0 : NEGC;
            o.y = adjv.y > 0.f ? sc[a][1] + su_ + swa[1] + c0 : NEGC;
            o.z = adjv.z > 0.f ? sc[a][2] + su_ + swa[2] + c0 : NEGC;
            o.w = adjv.w > 0.f ? sc[a][3] + su_ + swa[3] + c0 : NEGC;
            *(float4*)&lg[(n0s + a) * 64 + m0s] = o;
        }
    }
}

extern "C" void kernel_launch(void* const* d_in, const int* in_sizes, int n_in,
                              void* d_out, int out_size, void* d_ws, size_t ws_size,
                              hipStream_t stream) {
    (void)in_sizes; (void)n_in; (void)out_size; (void)ws_size;
    const float* obs     = (const float*)d_in[0];
    const float* W_drone = (const float*)d_in[1];
    const float* W_dock  = (const float*)d_in[2];
    const float* a_src   = (const float*)d_in[3];
    const float* a_dst   = (const float*)d_in[4];
    const float* Wc1     = (const float*)d_in[5];
    const float* bc1     = (const float*)d_in[6];
    const float* Wc2     = (const float*)d_in[7];
    const float* bc2     = (const float*)d_in[8];
    const float* Wad     = (const float*)d_in[9];
    const float* bad     = (const float*)d_in[10];
    const float* Wak     = (const float*)d_in[11];
    const float* bak     = (const float*)d_in[12];
    float* out = (float*)d_out;
    float* wsf = (float*)d_ws;

    setup_fold<<<dim3(17), dim3(256), 0, stream>>>(Wad, Wak, bad, bak, wsf);
    gat_fused<<<dim3(4096), dim3(256), 0, stream>>>(
        obs, W_drone, W_dock, a_src, a_dst,
        Wc1, bc1, Wc2, bc2, wsf,
        out, out + 4096);
}

// Round 3
// 309.950 us; speedup vs baseline: 3.0546x; 2.3836x over previous
//
#include <hip/hip_runtime.h>
#include <math.h>

#define OBSD 3584
#define NEGC -9e15f

typedef short short8 __attribute__((ext_vector_type(8)));
typedef float float4v __attribute__((ext_vector_type(4)));

// ---- ws element offsets ----
#define WS_MT_S   0        // short: Mt bf16 [128][128]  (Mt[i][r] = M[r][i])
#define WS_U_F    8192     // float: u[128]
#define WS_W_F    8320     // float: w[128]
#define WS_C0_F   8448     // float: c0
#define WS_AW_F   8452     // float: aw_dr[64], aw_dk[64]
#define WS_WDMT_S 17160    // short: wdmT bf16 [128][16]
#define WS_WFT_S  19208    // short: WflatT bf16 [128][64]

__device__ __forceinline__ float elu_f(float x) {
    return x > 0.f ? x : (__expf(x) - 1.f);
}
__device__ __forceinline__ short f2bf(float f) {
    union { float f; unsigned u; } v; v.f = f;
    unsigned u = v.u;
    unsigned r = (u + 0x7fffu + ((u >> 16) & 1u)) >> 16;
    return (short)r;
}
__device__ __forceinline__ float b2f(short s) {
    union { unsigned u; float f; } v; v.u = ((unsigned)(unsigned short)s) << 16;
    return v.f;
}
__device__ __forceinline__ unsigned pk2(float a, float b) {
    return (unsigned)(unsigned short)f2bf(a) | ((unsigned)(unsigned short)f2bf(b) << 16);
}

// =============== K0: weight folding ===============
__global__ __launch_bounds__(256) void setup_fold(
    const float* __restrict__ W_drone, const float* __restrict__ W_dock,
    const float* __restrict__ a_src, const float* __restrict__ a_dst,
    const float* __restrict__ Wad, const float* __restrict__ Wak,
    const float* __restrict__ bad, const float* __restrict__ bak,
    float* __restrict__ wsf, short* __restrict__ wss)
{
    const int t = threadIdx.x, bi = blockIdx.x;
    if (bi < 16) {
        __shared__ float sa[32 * 132];
        __shared__ float sb[32 * 132];
        const int r0 = (bi >> 2) * 32, i0 = (bi & 3) * 32;
        #pragma unroll
        for (int qq = 0; qq < 4; ++qq) {
            int e = (t + 256 * qq) * 4;
            int r = e >> 7, cc = e & 127;
            *(float4*)&sa[r * 132 + cc] = *(const float4*)&Wad[(r0 + r) * 128 + cc];
            *(float4*)&sb[r * 132 + cc] = *(const float4*)&Wak[(i0 + r) * 128 + cc];
        }
        __syncthreads();
        int rr = (t >> 4) * 2, ii = (t & 15) * 2;
        float a00 = 0.f, a01 = 0.f, a10 = 0.f, a11 = 0.f;
        for (int c = 0; c < 128; ++c) {
            float x0 = sa[rr * 132 + c], x1 = sa[(rr + 1) * 132 + c];
            float y0 = sb[ii * 132 + c], y1 = sb[(ii + 1) * 132 + c];
            a00 += x0 * y0; a01 += x0 * y1; a10 += x1 * y0; a11 += x1 * y1;
        }
        // Mt[i][r] = M[r][i]
        wss[WS_MT_S + (i0 + ii) * 128 + (r0 + rr)]         = f2bf(a00);
        wss[WS_MT_S + (i0 + ii + 1) * 128 + (r0 + rr)]     = f2bf(a01);
        wss[WS_MT_S + (i0 + ii) * 128 + (r0 + rr + 1)]     = f2bf(a10);
        wss[WS_MT_S + (i0 + ii + 1) * 128 + (r0 + rr + 1)] = f2bf(a11);
    } else if (bi == 16) {
        if (t < 128) {
            float acc = 0.f;
            for (int c = 0; c < 128; ++c) acc += Wad[t * 128 + c] * bak[c];
            wsf[WS_U_F + t] = acc;
        } else {
            int j = t - 128;
            float acc = 0.f;
            for (int c = 0; c < 128; ++c) acc += Wak[j * 128 + c] * bad[c];
            wsf[WS_W_F + j] = acc;
        }
        if (t == 0) {
            float acc = 0.f;
            for (int c = 0; c < 128; ++c) acc += bad[c] * bak[c];
            wsf[WS_C0_F] = acc;
        }
    } else {
        // aw vectors
        if (t < 64) {
            int h = t >> 4, f = t & 15;
            const float* wrow = W_drone + h * 2048 + f * 128;
            const float* arow = a_src + h * 128;
            float acc = 0.f;
            for (int k = 0; k < 128; ++k) acc += wrow[k] * arow[k];
            wsf[WS_AW_F + t] = acc;
        } else if (t < 128) {
            int tt = t - 64;
            int h = tt >> 4, f = tt & 15;
            const float* wrow = W_dock + h * 2048 + f * 128;
            const float* arow = a_dst + h * 128;
            float acc = 0.f;
            for (int k = 0; k < 128; ++k) acc += wrow[k] * arow[k];
            wsf[WS_AW_F + 64 + tt] = acc;
        }
        // wdmT[k2][f] = mean_h W_dock[h][f][k2]
        for (int idx = t; idx < 2048; idx += 256) {
            int k2 = idx >> 4, f = idx & 15;
            float v = 0.25f * (W_dock[f * 128 + k2] + W_dock[2048 + f * 128 + k2]
                             + W_dock[4096 + f * 128 + k2] + W_dock[6144 + f * 128 + k2]);
            wss[WS_WDMT_S + k2 * 16 + f] = f2bf(v);
        }
        // WflatT[k2][f64] = W_dock[f64>>4][f64&15][k2]
        for (int idx = t; idx < 8192; idx += 256) {
            int k2 = idx >> 6, f64 = idx & 63;
            float v = W_dock[(f64 >> 4) * 2048 + (f64 & 15) * 128 + k2];
            wss[WS_WFT_S + k2 * 64 + f64] = f2bf(v);
        }
    }
}

// =============== K1: attention -> hd (HD stashed in logits region) ===============
// LDS byte map:
//  sD  @0      droneT bf16 [16][32]
//  sK  @1024   dockT  bf16 [16][64]
//  sAdj@3072   adj    bf16 [32][72]
//  sAw @7680   f32 [128]
//  sSrc@8192   f32 [128]
//  sDst@8704   f32 [256]
//  sAt @9728   attn bf16 [4][32][72]
//  sT  @28160  T    bf16 [32][72]
//  sHd @32768  hd   bf16 [32][136]
//  sWf @41472  WflatT bf16 [128][64]
__global__ __launch_bounds__(256, 2) void k1_attn_hd(
    const float* __restrict__ obs,
    const float* __restrict__ wsf, const short* __restrict__ wss,
    short* __restrict__ hdg)
{
    __shared__ __align__(16) char sm[57856];
    short* sD   = (short*)(sm + 0);
    short* sK   = (short*)(sm + 1024);
    short* sAdj = (short*)(sm + 3072);
    float* sAw  = (float*)(sm + 7680);
    float* sSrc = (float*)(sm + 8192);
    float* sDst = (float*)(sm + 8704);
    short* sAt  = (short*)(sm + 9728);
    short* sT   = (short*)(sm + 28160);
    short* sHd  = (short*)(sm + 32768);
    short* sWf  = (short*)(sm + 41472);

    const int t = threadIdx.x;
    const int b = blockIdx.x;
    const float* obsrow = obs + (size_t)b * OBSD;
    const int L = t & 63, c = L & 15, q = L >> 4, w = t >> 6;

    // P0: obs -> LDS (bf16)
    #pragma unroll
    for (int i = 0; i < 4; ++i) {
        int q4 = t + 256 * i;
        if (q4 < 896) {
            float4 v = ((const float4*)obsrow)[q4];
            int e0 = q4 * 4;
            if (e0 < 512) {
                int n = e0 >> 4, f0 = e0 & 15;
                sD[(f0 + 0) * 32 + n] = f2bf(v.x);
                sD[(f0 + 1) * 32 + n] = f2bf(v.y);
                sD[(f0 + 2) * 32 + n] = f2bf(v.z);
                sD[(f0 + 3) * 32 + n] = f2bf(v.w);
            } else if (e0 < 1536) {
                int e = e0 - 512;
                int m = e >> 4, f0 = e & 15;
                sK[(f0 + 0) * 64 + m] = f2bf(v.x);
                sK[(f0 + 1) * 64 + m] = f2bf(v.y);
                sK[(f0 + 2) * 64 + m] = f2bf(v.z);
                sK[(f0 + 3) * 64 + m] = f2bf(v.w);
            } else {
                int e = e0 - 1536;
                int n = e >> 6, m0 = e & 63;
                uint2 pkd = { pk2(v.x, v.y), pk2(v.z, v.w) };
                *(uint2*)&sAdj[n * 72 + m0] = pkd;
            }
        }
    }
    // stage WflatT (16 KB) from ws
    #pragma unroll
    for (int i = 0; i < 4; ++i)
        ((uint4*)sWf)[t + 256 * i] = ((const uint4*)(wss + WS_WFT_S))[t + 256 * i];
    if (t < 128) sAw[t] = wsf[WS_AW_F + t];
    __syncthreads();

    // src[h][n], dst[h][m]
    if (t < 128) {
        int h = t >> 5, n = t & 31;
        float acc = 0.f;
        #pragma unroll
        for (int f = 0; f < 16; ++f) acc += b2f(sD[f * 32 + n]) * sAw[h * 16 + f];
        sSrc[h * 32 + n] = acc;
    }
    {
        int h = t >> 6, m = t & 63;
        float acc = 0.f;
        #pragma unroll
        for (int f = 0; f < 16; ++f) acc += b2f(sK[f * 64 + m]) * sAw[64 + h * 16 + f];
        sDst[h * 64 + m] = acc;
    }
    __syncthreads();

    // softmax: 2 lanes per row (128 rows = 4h x 32n)
    {
        int row = t >> 1, j = t & 1;
        int h = row >> 5, n = row & 31, m0 = j * 32;
        float sv = sSrc[h * 32 + n];
        float e32[32];
        float pmax = -INFINITY;
        #pragma unroll
        for (int mm = 0; mm < 32; ++mm) {
            int m = m0 + mm;
            float e = sv + sDst[h * 64 + m];
            e = e > 0.f ? e : 0.2f * e;
            e = (b2f(sAdj[n * 72 + m]) > 0.f) ? e : NEGC;
            e32[mm] = e;
            pmax = fmaxf(pmax, e);
        }
        pmax = fmaxf(pmax, __shfl_xor(pmax, 1, 2));
        float psum = 0.f;
        #pragma unroll
        for (int mm = 0; mm < 32; ++mm) { e32[mm] = __expf(e32[mm] - pmax); psum += e32[mm]; }
        psum += __shfl_xor(psum, 1, 2);
        float rinv = 1.f / psum;
        unsigned* ab = (unsigned*)sAt;
        int ub = (h * 2304 + n * 72 + m0) >> 1;
        #pragma unroll
        for (int mm = 0; mm < 32; mm += 2)
            ab[ub + (mm >> 1)] = pk2(e32[mm] * rinv, e32[mm + 1] * rinv);
    }
    __syncthreads();

    // T-GEMM: wave w handles head h=w: T[32][16] per head -> sT[32][72]
    {
        int h = w;
        float4v accT[2] = { {0,0,0,0}, {0,0,0,0} };
        #pragma unroll
        for (int mt = 0; mt < 2; ++mt)
            #pragma unroll
            for (int kq = 0; kq < 2; ++kq) {
                short8 a = *(const short8*)&sAt[h * 2304 + (mt * 16 + c) * 72 + kq * 32 + q * 8];
                short8 bb = *(const short8*)&sK[c * 64 + kq * 32 + q * 8];
                accT[mt] = __builtin_amdgcn_mfma_f32_16x16x32_bf16(a, bb, accT[mt], 0, 0, 0);
            }
        #pragma unroll
        for (int mt = 0; mt < 2; ++mt)
            #pragma unroll
            for (int i = 0; i < 4; ++i)
                sT[(mt * 16 + q * 4 + i) * 72 + h * 16 + c] = f2bf(accT[mt][i]);
    }
    __syncthreads();

    // hd-GEMM: hd = elu((T @ Wflat)/4); wave w: mt=w&1, nt in [(w>>1)*4, +4)
    {
        int mt = w & 1, ntb = (w >> 1) * 4;
        float4v acc[4] = { {0,0,0,0}, {0,0,0,0}, {0,0,0,0}, {0,0,0,0} };
        #pragma unroll
        for (int kq = 0; kq < 2; ++kq) {
            short8 a = *(const short8*)&sT[(mt * 16 + c) * 72 + kq * 32 + q * 8];
            #pragma unroll
            for (int p = 0; p < 4; ++p) {
                short8 bb = *(const short8*)&sWf[((ntb + p) * 16 + c) * 64 + kq * 32 + q * 8];
                acc[p] = __builtin_amdgcn_mfma_f32_16x16x32_bf16(a, bb, acc[p], 0, 0, 0);
            }
        }
        #pragma unroll
        for (int p = 0; p < 4; ++p)
            #pragma unroll
            for (int i = 0; i < 4; ++i) {
                float v = elu_f(acc[p][i] * 0.25f);
                sHd[(mt * 16 + q * 4 + i) * 136 + (ntb + p) * 16 + c] = f2bf(v);
            }
    }
    __syncthreads();

    // repack + coalesced global store of HD (bf16)
    {
        int n = t >> 3, k2 = (t & 7) * 16;
        uint4 x0 = *(const uint4*)&sHd[n * 136 + k2];
        uint4 x1 = *(const uint4*)&sHd[n * 136 + k2 + 8];
        uint4* dst = (uint4*)(hdg + (size_t)b * 4096 + n * 128 + k2);
        dst[0] = x0; dst[1] = x1;
    }
}

// =============== K2: critic GEMM: values = relu(HD@Wc1+bc1)@Wc2+bc2 ===============
__global__ __launch_bounds__(256) void k2_critic(
    const short* __restrict__ hdg,
    const float* __restrict__ Wc1, const float* __restrict__ bc1,
    const float* __restrict__ Wc2, const float* __restrict__ bc2,
    float* __restrict__ out_values)
{
    __shared__ __align__(16) char sm[46592];
    short* As   = (short*)(sm + 0);       // [64][72] bf16
    float* Wst  = (float*)(sm + 9216);    // [64][72] f32
    short* Bh   = (short*)(sm + 27648);   // [64][72] bf16
    short* Blo  = (short*)(sm + 36864);   // [64][72] bf16
    float* bc1L = (float*)(sm + 46080);
    float* wc2L = (float*)(sm + 46336);

    const int t = threadIdx.x;
    const int r0 = blockIdx.x * 64;
    const int L = t & 63, c = L & 15, q = L >> 4, w = t >> 6;

    if (t < 64) { bc1L[t] = bc1[t]; wc2L[t] = Wc2[t]; }

    float4v acc[4] = { {0,0,0,0}, {0,0,0,0}, {0,0,0,0}, {0,0,0,0} };

    for (int kc = 0; kc < 64; ++kc) {
        __syncthreads();
        {   // A chunk: HD rows r0..r0+63, k = kc*64..+63 (bf16)
            int r = t >> 2, kk0 = (t & 3) * 16;
            const uint4* src = (const uint4*)(hdg + (size_t)(r0 + r) * 4096 + kc * 64 + kk0);
            *(uint4*)&As[r * 72 + kk0]     = src[0];
            *(uint4*)&As[r * 72 + kk0 + 8] = src[1];
        }
        {   // Wc1 chunk fp32: rows e = kc*64..+63, cols 0..63
            int el = t >> 2, j0 = (t & 3) * 16;
            const float4* src = (const float4*)&Wc1[(size_t)(kc * 64 + el) * 64 + j0];
            #pragma unroll
            for (int u = 0; u < 4; ++u)
                *(float4*)&Wst[el * 72 + j0 + 4 * u] = src[u];
        }
        __syncthreads();
        {   // build Bt hi/lo: Bh[j][el] etc.
            int j = t & 63, elb = (t >> 6) * 16;
            #pragma unroll
            for (int e = 0; e < 16; e += 2) {
                float v0 = Wst[(elb + e) * 72 + j];
                float v1 = Wst[(elb + e + 1) * 72 + j];
                short h0 = f2bf(v0), h1 = f2bf(v1);
                float l0 = v0 - b2f(h0), l1 = v1 - b2f(h1);
                *(unsigned*)&Bh[j * 72 + elb + e]  = (unsigned)(unsigned short)h0 | ((unsigned)(unsigned short)h1 << 16);
                *(unsigned*)&Blo[j * 72 + elb + e] = (unsigned)(unsigned short)f2bf(l0) | ((unsigned)(unsigned short)f2bf(l1) << 16);
            }
        }
        __syncthreads();
        // MFMA: wave w owns row-tile rt=w
        #pragma unroll
        for (int kq = 0; kq < 2; ++kq) {
            short8 a = *(const short8*)&As[(w * 16 + c) * 72 + kq * 32 + q * 8];
            #pragma unroll
            for (int ct = 0; ct < 4; ++ct) {
                short8 bh = *(const short8*)&Bh[(ct * 16 + c) * 72 + kq * 32 + q * 8];
                short8 bl = *(const short8*)&Blo[(ct * 16 + c) * 72 + kq * 32 + q * 8];
                acc[ct] = __builtin_amdgcn_mfma_f32_16x16x32_bf16(a, bh, acc[ct], 0, 0, 0);
                acc[ct] = __builtin_amdgcn_mfma_f32_16x16x32_bf16(a, bl, acc[ct], 0, 0, 0);
            }
        }
    }
    // epilogue: relu + dot Wc2 + reduce across c lanes
    float bc2v = bc2[0];
    #pragma unroll
    for (int i = 0; i < 4; ++i) {
        float sv = 0.f;
        #pragma unroll
        for (int ct = 0; ct < 4; ++ct) {
            float pre = acc[ct][i] + bc1L[ct * 16 + c];
            pre = fmaxf(pre, 0.f);
            sv += pre * wc2L[ct * 16 + c];
        }
        sv += __shfl_xor(sv, 1, 16);
        sv += __shfl_xor(sv, 2, 16);
        sv += __shfl_xor(sv, 4, 16);
        sv += __shfl_xor(sv, 8, 16);
        if (c == 0) out_values[r0 + w * 16 + q * 4 + i] = sv + bc2v;
    }
}

// =============== K3: hk, t2, scores -> logits (overwrites HD bytes) ===============
// LDS byte map:
//  dockRm @0      bf16 [64][16]
//  adjBf  @2048   bf16 [32][72]
//  hdS    @6656   bf16 [32][136]
//  hkS    @15360  bf16 [64][136]
//  wdmTS  @32768  bf16 [128][16]   (dead after hk) / t2S bf16 [32][136]
//  suL    @41472  f32 [32]
//  swL    @41600  f32 [64]
//  uL     @41856  f32 [128]
//  wL     @42368  f32 [128]
//  MtS    @42880  bf16 [128][128]
__global__ __launch_bounds__(256, 2) void k3_logits(
    const float* __restrict__ obs,
    const float* __restrict__ wsf, const short* __restrict__ wss,
    float* __restrict__ out_logits)   // logits region; HD bytes live here too
{
    __shared__ __align__(16) char sm[75648];
    short* dockRm = (short*)(sm + 0);
    short* adjBf  = (short*)(sm + 2048);
    short* hdS    = (short*)(sm + 6656);
    short* hkS    = (short*)(sm + 15360);
    short* wdmTS  = (short*)(sm + 32768);
    short* t2S    = (short*)(sm + 32768);
    float* suL    = (float*)(sm + 41472);
    float* swL    = (float*)(sm + 41600);
    float* uL     = (float*)(sm + 41856);
    float* wL     = (float*)(sm + 42368);
    short* MtS    = (short*)(sm + 42880);

    const int t = threadIdx.x;
    const int b = blockIdx.x;
    const float* obsrow = obs + (size_t)b * OBSD;
    short* hdg = (short*)out_logits;   // HD bf16 [4096][4096] occupies logits bytes
    const int L = t & 63, c = L & 15, q = L >> 4, w = t >> 6;

    // load HD rows for this batch
    {
        int n = t >> 3, k2 = (t & 7) * 16;
        const uint4* src = (const uint4*)(hdg + (size_t)b * 4096 + n * 128 + k2);
        uint4 x0 = src[0], x1 = src[1];
        *(uint4*)&hdS[n * 136 + k2]     = x0;
        *(uint4*)&hdS[n * 136 + k2 + 8] = x1;
    }
    // dock rows (bf16, row-major)
    {
        float4 v = ((const float4*)obsrow)[128 + t];
        int m = t >> 2, f0 = (t & 3) * 4;
        uint2 pkd = { pk2(v.x, v.y), pk2(v.z, v.w) };
        *(uint2*)&dockRm[m * 16 + f0] = pkd;
    }
    // adj
    #pragma unroll
    for (int i = 0; i < 2; ++i) {
        int q4 = 384 + t + 256 * i;
        if (q4 < 896) {
            float4 v = ((const float4*)obsrow)[q4];
            int e = q4 * 4 - 1536;
            int n = e >> 6, m0 = e & 63;
            uint2 pkd = { pk2(v.x, v.y), pk2(v.z, v.w) };
            *(uint2*)&adjBf[n * 72 + m0] = pkd;
        }
    }
    // stage wdmT (4 KB), Mt (32 KB), u, w
    ((uint4*)wdmTS)[t] = ((const uint4*)(wss + WS_WDMT_S))[t];
    #pragma unroll
    for (int i = 0; i < 8; ++i)
        ((uint4*)MtS)[t + 256 * i] = ((const uint4*)(wss + WS_MT_S))[t + 256 * i];
    if (t < 128) uL[t] = wsf[WS_U_F + t];
    else wL[t - 128] = wsf[WS_W_F + (t - 128)];
    __syncthreads();

    // hk-GEMM: hk = elu(dock @ wdm); wave w: m-tile mt=w, nt 0..7; K=16 (zero-padded)
    {
        int mt = w;
        short8 a;
        if (q < 2) a = *(const short8*)&dockRm[(mt * 16 + c) * 16 + q * 8];
        else a = short8{0, 0, 0, 0, 0, 0, 0, 0};
        float swp[4] = {0.f, 0.f, 0.f, 0.f};
        #pragma unroll
        for (int nt = 0; nt < 8; ++nt) {
            short8 bb;
            if (q < 2) bb = *(const short8*)&wdmTS[(nt * 16 + c) * 16 + q * 8];
            else bb = short8{0, 0, 0, 0, 0, 0, 0, 0};
            float4v acc = {0, 0, 0, 0};
            acc = __builtin_amdgcn_mfma_f32_16x16x32_bf16(a, bb, acc, 0, 0, 0);
            float wv = wL[nt * 16 + c];
            #pragma unroll
            for (int i = 0; i < 4; ++i) {
                float ev = elu_f(acc[i]);
                hkS[(mt * 16 + q * 4 + i) * 136 + nt * 16 + c] = f2bf(ev);
                swp[i] += ev * wv;
            }
        }
        #pragma unroll
        for (int i = 0; i < 4; ++i) {
            float sv = swp[i];
            sv += __shfl_xor(sv, 1, 16);
            sv += __shfl_xor(sv, 2, 16);
            sv += __shfl_xor(sv, 4, 16);
            sv += __shfl_xor(sv, 8, 16);
            if (c == 0) swL[mt * 16 + q * 4 + i] = sv;
        }
    }
    // su[n] = hd[n] . u  (8 partials per row)
    {
        int n = t >> 3, p = t & 7;
        float a = 0.f;
        #pragma unroll
        for (int kk = 0; kk < 16; kk += 2) {
            unsigned uu = *(const unsigned*)&hdS[n * 136 + p * 16 + kk];
            a += b2f((short)(uu & 0xffff)) * uL[p * 16 + kk]
               + b2f((short)(uu >> 16))   * uL[p * 16 + kk + 1];
        }
        a += __shfl_xor(a, 1, 8);
        a += __shfl_xor(a, 2, 8);
        a += __shfl_xor(a, 4, 8);
        if (p == 0) suL[n] = a;
    }
    __syncthreads();

    // t2-GEMM: t2 = hd @ M; wave w: mt=w&1, nt in [(w>>1)*4,+4); K=128
    {
        int mt = w & 1, ntb = (w >> 1) * 4;
        float4v acc[4] = { {0,0,0,0}, {0,0,0,0}, {0,0,0,0}, {0,0,0,0} };
        #pragma unroll
        for (int kq = 0; kq < 4; ++kq) {
            short8 a = *(const short8*)&hdS[(mt * 16 + c) * 136 + kq * 32 + q * 8];
            #pragma unroll
            for (int p = 0; p < 4; ++p) {
                short8 bb = *(const short8*)&MtS[((ntb + p) * 16 + c) * 128 + kq * 32 + q * 8];
                acc[p] = __builtin_amdgcn_mfma_f32_16x16x32_bf16(a, bb, acc[p], 0, 0, 0);
            }
        }
        __syncthreads();   // wdmTS dead; safe to overwrite with t2
        #pragma unroll
        for (int p = 0; p < 4; ++p)
            #pragma unroll
            for (int i = 0; i < 4; ++i)
                t2S[(mt * 16 + q * 4 + i) * 136 + (ntb + p) * 16 + c] = f2bf(acc[p][i]);
    }
    __syncthreads();

    // scores-GEMM: scores = t2 @ hk^T + su + sw + c0, mask, store
    {
        const float c0v = wsf[WS_C0_F];
        int ntd = w;
        float* lg = out_logits + (size_t)b * 2048;
        #pragma unroll
        for (int mt = 0; mt < 2; ++mt) {
            float4v acc = {0, 0, 0, 0};
            #pragma unroll
            for (int kq = 0; kq < 4; ++kq) {
                short8 a  = *(const short8*)&t2S[(mt * 16 + c) * 136 + kq * 32 + q * 8];
                short8 bb = *(const short8*)&hkS[(ntd * 16 + c) * 136 + kq * 32 + q * 8];
                acc = __builtin_amdgcn_mfma_f32_16x16x32_bf16(a, bb, acc, 0, 0, 0);
            }
            int col = ntd * 16 + c;
            float swv = swL[col];
            #pragma unroll
            for (int i = 0; i < 4; ++i) {
                int row = mt * 16 + q * 4 + i;
                float val = acc[i] + suL[row] + swv + c0v;
                bool keep = b2f(adjBf[row * 72 + col]) > 0.f;
                lg[row * 64 + col] = keep ? val : NEGC;
            }
        }
    }
}

extern "C" void kernel_launch(void* const* d_in, const int* in_sizes, int n_in,
                              void* d_out, int out_size, void* d_ws, size_t ws_size,
                              hipStream_t stream) {
    (void)in_sizes; (void)n_in; (void)out_size; (void)ws_size;
    const float* obs     = (const float*)d_in[0];
    const float* W_drone = (const float*)d_in[1];
    const float* W_dock  = (const float*)d_in[2];
    const float* a_src   = (const float*)d_in[3];
    const float* a_dst   = (const float*)d_in[4];
    const float* Wc1     = (const float*)d_in[5];
    const float* bc1     = (const float*)d_in[6];
    const float* Wc2     = (const float*)d_in[7];
    const float* bc2     = (const float*)d_in[8];
    const float* Wad     = (const float*)d_in[9];
    const float* bad     = (const float*)d_in[10];
    const float* Wak     = (const float*)d_in[11];
    const float* bak     = (const float*)d_in[12];
    float* out = (float*)d_out;
    float* wsf = (float*)d_ws;
    short* wss = (short*)d_ws;
    short* hdg = (short*)(out + 4096);     // HD bf16 stashed in logits region

    setup_fold<<<dim3(18), dim3(256), 0, stream>>>(
        W_drone, W_dock, a_src, a_dst, Wad, Wak, bad, bak, wsf, wss);
    k1_attn_hd<<<dim3(4096), dim3(256), 0, stream>>>(obs, wsf, wss, hdg);
    k2_critic<<<dim3(64), dim3(256), 0, stream>>>(hdg, Wc1, bc1, Wc2, bc2, out);
    k3_logits<<<dim3(4096), dim3(256), 0, stream>>>(obs, wsf, wss, out + 4096);
}

// Round 4
// 263.266 us; speedup vs baseline: 3.5963x; 1.1773x over previous
//
#include <hip/hip_runtime.h>
#include <math.h>

#define OBSD 3584
#define NEGC -9e15f

typedef short short8 __attribute__((ext_vector_type(8)));
typedef float float4v __attribute__((ext_vector_type(4)));

// ---- ws element offsets ----
#define WS_MT_S   0        // short: Mt bf16 [128][128]  (Mt[i][r] = M[r][i])
#define WS_U_F    8192     // float: u[128]
#define WS_W_F    8320     // float: w[128]
#define WS_C0_F   8448     // float: c0
#define WS_AW_F   8452     // float: aw_dr[64], aw_dk[64]
#define WS_WDMT_S 17160    // short: wdmT bf16 [128][16]
#define WS_WFT_S  19208    // short: WflatT bf16 [128][64]
#define WS_WC1H_S 32768    // short: Wc1T hi bf16 [64][4096]
#define WS_WC1L_S 294912   // short: Wc1T lo bf16 [64][4096]
#define WS_NEED_BYTES 1114112ull

__device__ __forceinline__ float elu_f(float x) {
    return x > 0.f ? x : (__expf(x) - 1.f);
}
__device__ __forceinline__ short f2bf(float f) {
    union { float f; unsigned u; } v; v.f = f;
    unsigned u = v.u;
    unsigned r = (u + 0x7fffu + ((u >> 16) & 1u)) >> 16;
    return (short)r;
}
__device__ __forceinline__ float b2f(short s) {
    union { unsigned u; float f; } v; v.u = ((unsigned)(unsigned short)s) << 16;
    return v.f;
}
__device__ __forceinline__ unsigned pk2(float a, float b) {
    return (unsigned)(unsigned short)f2bf(a) | ((unsigned)(unsigned short)f2bf(b) << 16);
}

// =============== K0: weight folding ===============
__global__ __launch_bounds__(256) void setup_fold(
    const float* __restrict__ W_drone, const float* __restrict__ W_dock,
    const float* __restrict__ a_src, const float* __restrict__ a_dst,
    const float* __restrict__ Wad, const float* __restrict__ Wak,
    const float* __restrict__ bad, const float* __restrict__ bak,
    float* __restrict__ wsf, short* __restrict__ wss)
{
    const int t = threadIdx.x, bi = blockIdx.x;
    if (bi < 16) {
        __shared__ float sa[32 * 132];
        __shared__ float sb[32 * 132];
        const int r0 = (bi >> 2) * 32, i0 = (bi & 3) * 32;
        #pragma unroll
        for (int qq = 0; qq < 4; ++qq) {
            int e = (t + 256 * qq) * 4;
            int r = e >> 7, cc = e & 127;
            *(float4*)&sa[r * 132 + cc] = *(const float4*)&Wad[(r0 + r) * 128 + cc];
            *(float4*)&sb[r * 132 + cc] = *(const float4*)&Wak[(i0 + r) * 128 + cc];
        }
        __syncthreads();
        int rr = (t >> 4) * 2, ii = (t & 15) * 2;
        float a00 = 0.f, a01 = 0.f, a10 = 0.f, a11 = 0.f;
        for (int c = 0; c < 128; ++c) {
            float x0 = sa[rr * 132 + c], x1 = sa[(rr + 1) * 132 + c];
            float y0 = sb[ii * 132 + c], y1 = sb[(ii + 1) * 132 + c];
            a00 += x0 * y0; a01 += x0 * y1; a10 += x1 * y0; a11 += x1 * y1;
        }
        // Mt[i][r] = M[r][i]
        wss[WS_MT_S + (i0 + ii) * 128 + (r0 + rr)]         = f2bf(a00);
        wss[WS_MT_S + (i0 + ii + 1) * 128 + (r0 + rr)]     = f2bf(a01);
        wss[WS_MT_S + (i0 + ii) * 128 + (r0 + rr + 1)]     = f2bf(a10);
        wss[WS_MT_S + (i0 + ii + 1) * 128 + (r0 + rr + 1)] = f2bf(a11);
    } else if (bi == 16) {
        if (t < 128) {
            float acc = 0.f;
            for (int c = 0; c < 128; ++c) acc += Wad[t * 128 + c] * bak[c];
            wsf[WS_U_F + t] = acc;
        } else {
            int j = t - 128;
            float acc = 0.f;
            for (int c = 0; c < 128; ++c) acc += Wak[j * 128 + c] * bad[c];
            wsf[WS_W_F + j] = acc;
        }
        if (t == 0) {
            float acc = 0.f;
            for (int c = 0; c < 128; ++c) acc += bad[c] * bak[c];
            wsf[WS_C0_F] = acc;
        }
    } else {
        // aw vectors
        if (t < 64) {
            int h = t >> 4, f = t & 15;
            const float* wrow = W_drone + h * 2048 + f * 128;
            const float* arow = a_src + h * 128;
            float acc = 0.f;
            for (int k = 0; k < 128; ++k) acc += wrow[k] * arow[k];
            wsf[WS_AW_F + t] = acc;
        } else if (t < 128) {
            int tt = t - 64;
            int h = tt >> 4, f = tt & 15;
            const float* wrow = W_dock + h * 2048 + f * 128;
            const float* arow = a_dst + h * 128;
            float acc = 0.f;
            for (int k = 0; k < 128; ++k) acc += wrow[k] * arow[k];
            wsf[WS_AW_F + 64 + tt] = acc;
        }
        // wdmT[k2][f] = mean_h W_dock[h][f][k2]
        for (int idx = t; idx < 2048; idx += 256) {
            int k2 = idx >> 4, f = idx & 15;
            float v = 0.25f * (W_dock[f * 128 + k2] + W_dock[2048 + f * 128 + k2]
                             + W_dock[4096 + f * 128 + k2] + W_dock[6144 + f * 128 + k2]);
            wss[WS_WDMT_S + k2 * 16 + f] = f2bf(v);
        }
        // WflatT[k2][f64] = W_dock[f64>>4][f64&15][k2]
        for (int idx = t; idx < 8192; idx += 256) {
            int k2 = idx >> 6, f64 = idx & 63;
            float v = W_dock[(f64 >> 4) * 2048 + (f64 & 15) * 128 + k2];
            wss[WS_WFT_S + k2 * 64 + f64] = f2bf(v);
        }
    }
}

// =============== K0b: Wc1 -> transposed bf16 hi/lo ===============
__global__ __launch_bounds__(256) void setup_wc1(
    const float* __restrict__ Wc1,
    short* __restrict__ wc1h, short* __restrict__ wc1l)
{
    const int col = blockIdx.x;          // 0..63
    for (int k = threadIdx.x; k < 4096; k += 256) {
        float v = Wc1[(size_t)k * 64 + col];
        short hi = f2bf(v);
        float lo = v - b2f(hi);
        wc1h[col * 4096 + k] = hi;
        wc1l[col * 4096 + k] = f2bf(lo);
    }
}

// =============== K1: attention -> hd (HD stashed in logits region) ===============
// LDS byte map:
//  sD  @0      droneT bf16 [16][32]
//  sK  @1024   dockT  bf16 [16][64]
//  sAdj@3072   adj    bf16 [32][72]
//  sAw @7680   f32 [128]
//  sSrc@8192   f32 [128]
//  sDst@8704   f32 [256]
//  sAt @9728   attn bf16 [4][32][72]
//  sT  @28160  T    bf16 [32][72]
//  sHd @32768  hd   bf16 [32][136]
//  sWf @41472  WflatT bf16 [128][64]
__global__ __launch_bounds__(256, 2) void k1_attn_hd(
    const float* __restrict__ obs,
    const float* __restrict__ wsf, const short* __restrict__ wss,
    short* __restrict__ hdg)
{
    __shared__ __align__(16) char sm[57856];
    short* sD   = (short*)(sm + 0);
    short* sK   = (short*)(sm + 1024);
    short* sAdj = (short*)(sm + 3072);
    float* sAw  = (float*)(sm + 7680);
    float* sSrc = (float*)(sm + 8192);
    float* sDst = (float*)(sm + 8704);
    short* sAt  = (short*)(sm + 9728);
    short* sT   = (short*)(sm + 28160);
    short* sHd  = (short*)(sm + 32768);
    short* sWf  = (short*)(sm + 41472);

    const int t = threadIdx.x;
    const int b = blockIdx.x;
    const float* obsrow = obs + (size_t)b * OBSD;
    const int L = t & 63, c = L & 15, q = L >> 4, w = t >> 6;

    // P0: obs -> LDS (bf16)
    #pragma unroll
    for (int i = 0; i < 4; ++i) {
        int q4 = t + 256 * i;
        if (q4 < 896) {
            float4 v = ((const float4*)obsrow)[q4];
            int e0 = q4 * 4;
            if (e0 < 512) {
                int n = e0 >> 4, f0 = e0 & 15;
                sD[(f0 + 0) * 32 + n] = f2bf(v.x);
                sD[(f0 + 1) * 32 + n] = f2bf(v.y);
                sD[(f0 + 2) * 32 + n] = f2bf(v.z);
                sD[(f0 + 3) * 32 + n] = f2bf(v.w);
            } else if (e0 < 1536) {
                int e = e0 - 512;
                int m = e >> 4, f0 = e & 15;
                sK[(f0 + 0) * 64 + m] = f2bf(v.x);
                sK[(f0 + 1) * 64 + m] = f2bf(v.y);
                sK[(f0 + 2) * 64 + m] = f2bf(v.z);
                sK[(f0 + 3) * 64 + m] = f2bf(v.w);
            } else {
                int e = e0 - 1536;
                int n = e >> 6, m0 = e & 63;
                uint2 pkd = { pk2(v.x, v.y), pk2(v.z, v.w) };
                *(uint2*)&sAdj[n * 72 + m0] = pkd;
            }
        }
    }
    // stage WflatT (16 KB) from ws
    #pragma unroll
    for (int i = 0; i < 4; ++i)
        ((uint4*)sWf)[t + 256 * i] = ((const uint4*)(wss + WS_WFT_S))[t + 256 * i];
    if (t < 128) sAw[t] = wsf[WS_AW_F + t];
    __syncthreads();

    // src[h][n], dst[h][m]
    if (t < 128) {
        int h = t >> 5, n = t & 31;
        float acc = 0.f;
        #pragma unroll
        for (int f = 0; f < 16; ++f) acc += b2f(sD[f * 32 + n]) * sAw[h * 16 + f];
        sSrc[h * 32 + n] = acc;
    }
    {
        int h = t >> 6, m = t & 63;
        float acc = 0.f;
        #pragma unroll
        for (int f = 0; f < 16; ++f) acc += b2f(sK[f * 64 + m]) * sAw[64 + h * 16 + f];
        sDst[h * 64 + m] = acc;
    }
    __syncthreads();

    // softmax: 2 lanes per row (128 rows = 4h x 32n)
    {
        int row = t >> 1, j = t & 1;
        int h = row >> 5, n = row & 31, m0 = j * 32;
        float sv = sSrc[h * 32 + n];
        float e32[32];
        float pmax = -INFINITY;
        #pragma unroll
        for (int mm = 0; mm < 32; ++mm) {
            int m = m0 + mm;
            float e = sv + sDst[h * 64 + m];
            e = e > 0.f ? e : 0.2f * e;
            e = (b2f(sAdj[n * 72 + m]) > 0.f) ? e : NEGC;
            e32[mm] = e;
            pmax = fmaxf(pmax, e);
        }
        pmax = fmaxf(pmax, __shfl_xor(pmax, 1, 2));
        float psum = 0.f;
        #pragma unroll
        for (int mm = 0; mm < 32; ++mm) { e32[mm] = __expf(e32[mm] - pmax); psum += e32[mm]; }
        psum += __shfl_xor(psum, 1, 2);
        float rinv = 1.f / psum;
        unsigned* ab = (unsigned*)sAt;
        int ub = (h * 2304 + n * 72 + m0) >> 1;
        #pragma unroll
        for (int mm = 0; mm < 32; mm += 2)
            ab[ub + (mm >> 1)] = pk2(e32[mm] * rinv, e32[mm + 1] * rinv);
    }
    __syncthreads();

    // T-GEMM: wave w handles head h=w: T[32][16] per head -> sT[32][72]
    {
        int h = w;
        float4v accT[2] = { {0,0,0,0}, {0,0,0,0} };
        #pragma unroll
        for (int mt = 0; mt < 2; ++mt)
            #pragma unroll
            for (int kq = 0; kq < 2; ++kq) {
                short8 a = *(const short8*)&sAt[h * 2304 + (mt * 16 + c) * 72 + kq * 32 + q * 8];
                short8 bb = *(const short8*)&sK[c * 64 + kq * 32 + q * 8];
                accT[mt] = __builtin_amdgcn_mfma_f32_16x16x32_bf16(a, bb, accT[mt], 0, 0, 0);
            }
        #pragma unroll
        for (int mt = 0; mt < 2; ++mt)
            #pragma unroll
            for (int i = 0; i < 4; ++i)
                sT[(mt * 16 + q * 4 + i) * 72 + h * 16 + c] = f2bf(accT[mt][i]);
    }
    __syncthreads();

    // hd-GEMM: hd = elu((T @ Wflat)/4); wave w: mt=w&1, nt in [(w>>1)*4, +4)
    {
        int mt = w & 1, ntb = (w >> 1) * 4;
        float4v acc[4] = { {0,0,0,0}, {0,0,0,0}, {0,0,0,0}, {0,0,0,0} };
        #pragma unroll
        for (int kq = 0; kq < 2; ++kq) {
            short8 a = *(const short8*)&sT[(mt * 16 + c) * 72 + kq * 32 + q * 8];
            #pragma unroll
            for (int p = 0; p < 4; ++p) {
                short8 bb = *(const short8*)&sWf[((ntb + p) * 16 + c) * 64 + kq * 32 + q * 8];
                acc[p] = __builtin_amdgcn_mfma_f32_16x16x32_bf16(a, bb, acc[p], 0, 0, 0);
            }
        }
        #pragma unroll
        for (int p = 0; p < 4; ++p)
            #pragma unroll
            for (int i = 0; i < 4; ++i) {
                float v = elu_f(acc[p][i] * 0.25f);
                sHd[(mt * 16 + q * 4 + i) * 136 + (ntb + p) * 16 + c] = f2bf(v);
            }
    }
    __syncthreads();

    // repack + coalesced global store of HD (bf16)
    {
        int n = t >> 3, k2 = (t & 7) * 16;
        uint4 x0 = *(const uint4*)&sHd[n * 136 + k2];
        uint4 x1 = *(const uint4*)&sHd[n * 136 + k2 + 8];
        uint4* dst = (uint4*)(hdg + (size_t)b * 4096 + n * 128 + k2);
        dst[0] = x0; dst[1] = x1;
    }
}

// =============== K2 (fallback): critic GEMM, 64 blocks ===============
__global__ __launch_bounds__(256) void k2_critic(
    const short* __restrict__ hdg,
    const float* __restrict__ Wc1, const float* __restrict__ bc1,
    const float* __restrict__ Wc2, const float* __restrict__ bc2,
    float* __restrict__ out_values)
{
    __shared__ __align__(16) char sm[46592];
    short* As   = (short*)(sm + 0);       // [64][72] bf16
    float* Wst  = (float*)(sm + 9216);    // [64][72] f32
    short* Bh   = (short*)(sm + 27648);   // [64][72] bf16
    short* Blo  = (short*)(sm + 36864);   // [64][72] bf16
    float* bc1L = (float*)(sm + 46080);
    float* wc2L = (float*)(sm + 46336);

    const int t = threadIdx.x;
    const int r0 = blockIdx.x * 64;
    const int L = t & 63, c = L & 15, q = L >> 4, w = t >> 6;

    if (t < 64) { bc1L[t] = bc1[t]; wc2L[t] = Wc2[t]; }

    float4v acc[4] = { {0,0,0,0}, {0,0,0,0}, {0,0,0,0}, {0,0,0,0} };

    for (int kc = 0; kc < 64; ++kc) {
        __syncthreads();
        {
            int r = t >> 2, kk0 = (t & 3) * 16;
            const uint4* src = (const uint4*)(hdg + (size_t)(r0 + r) * 4096 + kc * 64 + kk0);
            *(uint4*)&As[r * 72 + kk0]     = src[0];
            *(uint4*)&As[r * 72 + kk0 + 8] = src[1];
        }
        {
            int el = t >> 2, j0 = (t & 3) * 16;
            const float4* src = (const float4*)&Wc1[(size_t)(kc * 64 + el) * 64 + j0];
            #pragma unroll
            for (int u = 0; u < 4; ++u)
                *(float4*)&Wst[el * 72 + j0 + 4 * u] = src[u];
        }
        __syncthreads();
        {
            int j = t & 63, elb = (t >> 6) * 16;
            #pragma unroll
            for (int e = 0; e < 16; e += 2) {
                float v0 = Wst[(elb + e) * 72 + j];
                float v1 = Wst[(elb + e + 1) * 72 + j];
                short h0 = f2bf(v0), h1 = f2bf(v1);
                float l0 = v0 - b2f(h0), l1 = v1 - b2f(h1);
                *(unsigned*)&Bh[j * 72 + elb + e]  = (unsigned)(unsigned short)h0 | ((unsigned)(unsigned short)h1 << 16);
                *(unsigned*)&Blo[j * 72 + elb + e] = (unsigned)(unsigned short)f2bf(l0) | ((unsigned)(unsigned short)f2bf(l1) << 16);
            }
        }
        __syncthreads();
        #pragma unroll
        for (int kq = 0; kq < 2; ++kq) {
            short8 a = *(const short8*)&As[(w * 16 + c) * 72 + kq * 32 + q * 8];
            #pragma unroll
            for (int ct = 0; ct < 4; ++ct) {
                short8 bh = *(const short8*)&Bh[(ct * 16 + c) * 72 + kq * 32 + q * 8];
                short8 bl = *(const short8*)&Blo[(ct * 16 + c) * 72 + kq * 32 + q * 8];
                acc[ct] = __builtin_amdgcn_mfma_f32_16x16x32_bf16(a, bh, acc[ct], 0, 0, 0);
                acc[ct] = __builtin_amdgcn_mfma_f32_16x16x32_bf16(a, bl, acc[ct], 0, 0, 0);
            }
        }
    }
    float bc2v = bc2[0];
    #pragma unroll
    for (int i = 0; i < 4; ++i) {
        float sv = 0.f;
        #pragma unroll
        for (int ct = 0; ct < 4; ++ct) {
            float pre = acc[ct][i] + bc1L[ct * 16 + c];
            pre = fmaxf(pre, 0.f);
            sv += pre * wc2L[ct * 16 + c];
        }
        sv += __shfl_xor(sv, 1, 16);
        sv += __shfl_xor(sv, 2, 16);
        sv += __shfl_xor(sv, 4, 16);
        sv += __shfl_xor(sv, 8, 16);
        if (c == 0) out_values[r0 + w * 16 + q * 4 + i] = sv + bc2v;
    }
}

// =============== K2 (fast): critic GEMM, 256 blocks x 16 rows ===============
// LDS: As[16][136] @0 (4352 B), Bh[64][136] @4352 (17408), Bl @21760 (17408),
//      bc1L @39168, wc2L @39424, red @39680 (4*16 f32) -> 39936 B total
__global__ __launch_bounds__(256) void k2_critic2(
    const short* __restrict__ hdg,
    const short* __restrict__ wc1h, const short* __restrict__ wc1l,
    const float* __restrict__ bc1,
    const float* __restrict__ Wc2, const float* __restrict__ bc2,
    float* __restrict__ out_values)
{
    __shared__ __align__(16) char sm[39936];
    short* As   = (short*)(sm + 0);
    short* Bh   = (short*)(sm + 4352);
    short* Bl   = (short*)(sm + 21760);
    float* bc1L = (float*)(sm + 39168);
    float* wc2L = (float*)(sm + 39424);
    float* red  = (float*)(sm + 39680);

    const int t = threadIdx.x;
    const int r0 = blockIdx.x * 16;
    const int L = t & 63, c = L & 15, q = L >> 4, w = t >> 6;

    if (t < 64) { bc1L[t] = bc1[t]; wc2L[t] = Wc2[t]; }

    float4v acc = {0, 0, 0, 0};

    const int rA  = t >> 4,  kkA = (t & 15) * 8;   // A stage: 16 rows x 128 k
    const int colB = t >> 2, kbB = (t & 3) * 32;   // B stage: 64 cols x 128 k

    for (int it = 0; it < 32; ++it) {
        const int kc = it * 128;
        __syncthreads();
        *(uint4*)&As[rA * 136 + kkA] =
            *(const uint4*)(hdg + (size_t)(r0 + rA) * 4096 + kc + kkA);
        {
            const uint4* srcH = (const uint4*)(wc1h + (size_t)colB * 4096 + kc + kbB);
            const uint4* srcL = (const uint4*)(wc1l + (size_t)colB * 4096 + kc + kbB);
            #pragma unroll
            for (int u = 0; u < 4; ++u) {
                *(uint4*)&Bh[colB * 136 + kbB + 8 * u] = srcH[u];
                *(uint4*)&Bl[colB * 136 + kbB + 8 * u] = srcL[u];
            }
        }
        __syncthreads();
        #pragma unroll
        for (int kq = 0; kq < 4; ++kq) {
            short8 a  = *(const short8*)&As[c * 136 + kq * 32 + q * 8];
            short8 bh = *(const short8*)&Bh[(w * 16 + c) * 136 + kq * 32 + q * 8];
            short8 bl = *(const short8*)&Bl[(w * 16 + c) * 136 + kq * 32 + q * 8];
            acc = __builtin_amdgcn_mfma_f32_16x16x32_bf16(a, bh, acc, 0, 0, 0);
            acc = __builtin_amdgcn_mfma_f32_16x16x32_bf16(a, bl, acc, 0, 0, 0);
        }
    }
    // epilogue: relu + dot Wc2 over this wave's 16 cols, reduce over c lanes
    #pragma unroll
    for (int i = 0; i < 4; ++i) {
        float pre = acc[i] + bc1L[w * 16 + c];
        pre = fmaxf(pre, 0.f);
        float sv = pre * wc2L[w * 16 + c];
        sv += __shfl_xor(sv, 1, 16);
        sv += __shfl_xor(sv, 2, 16);
        sv += __shfl_xor(sv, 4, 16);
        sv += __shfl_xor(sv, 8, 16);
        if (c == 0) red[w * 16 + q * 4 + i] = sv;
    }
    __syncthreads();
    if (t < 16) {
        float v = red[t] + red[16 + t] + red[32 + t] + red[48 + t] + bc2[0];
        out_values[r0 + t] = v;
    }
}

// =============== K3: hk, t2, scores -> logits (overwrites HD bytes) ===============
// LDS byte map:
//  dockRm @0      bf16 [64][16]
//  adjBf  @2048   bf16 [32][72]
//  hdS    @6656   bf16 [32][136]
//  hkS    @15360  bf16 [64][136]
//  wdmTS  @32768  bf16 [128][16]   (dead after hk) / t2S bf16 [32][136]
//  suL    @41472  f32 [32]
//  swL    @41600  f32 [64]
//  uL     @41856  f32 [128]
//  wL     @42368  f32 [128]
//  MtS    @42880  bf16 [128][128]
__global__ __launch_bounds__(256, 2) void k3_logits(
    const float* __restrict__ obs,
    const float* __restrict__ wsf, const short* __restrict__ wss,
    float* __restrict__ out_logits)   // logits region; HD bytes live here too
{
    __shared__ __align__(16) char sm[75648];
    short* dockRm = (short*)(sm + 0);
    short* adjBf  = (short*)(sm + 2048);
    short* hdS    = (short*)(sm + 6656);
    short* hkS    = (short*)(sm + 15360);
    short* wdmTS  = (short*)(sm + 32768);
    short* t2S    = (short*)(sm + 32768);
    float* suL    = (float*)(sm + 41472);
    float* swL    = (float*)(sm + 41600);
    float* uL     = (float*)(sm + 41856);
    float* wL     = (float*)(sm + 42368);
    short* MtS    = (short*)(sm + 42880);

    const int t = threadIdx.x;
    const int b = blockIdx.x;
    const float* obsrow = obs + (size_t)b * OBSD;
    short* hdg = (short*)out_logits;   // HD bf16 stashed in logits bytes
    const int L = t & 63, c = L & 15, q = L >> 4, w = t >> 6;

    // load HD rows for this batch
    {
        int n = t >> 3, k2 = (t & 7) * 16;
        const uint4* src = (const uint4*)(hdg + (size_t)b * 4096 + n * 128 + k2);
        uint4 x0 = src[0], x1 = src[1];
        *(uint4*)&hdS[n * 136 + k2]     = x0;
        *(uint4*)&hdS[n * 136 + k2 + 8] = x1;
    }
    // dock rows (bf16, row-major)
    {
        float4 v = ((const float4*)obsrow)[128 + t];
        int m = t >> 2, f0 = (t & 3) * 4;
        uint2 pkd = { pk2(v.x, v.y), pk2(v.z, v.w) };
        *(uint2*)&dockRm[m * 16 + f0] = pkd;
    }
    // adj
    #pragma unroll
    for (int i = 0; i < 2; ++i) {
        int q4 = 384 + t + 256 * i;
        if (q4 < 896) {
            float4 v = ((const float4*)obsrow)[q4];
            int e = q4 * 4 - 1536;
            int n = e >> 6, m0 = e & 63;
            uint2 pkd = { pk2(v.x, v.y), pk2(v.z, v.w) };
            *(uint2*)&adjBf[n * 72 + m0] = pkd;
        }
    }
    // stage wdmT (4 KB), Mt (32 KB), u, w
    ((uint4*)wdmTS)[t] = ((const uint4*)(wss + WS_WDMT_S))[t];
    #pragma unroll
    for (int i = 0; i < 8; ++i)
        ((uint4*)MtS)[t + 256 * i] = ((const uint4*)(wss + WS_MT_S))[t + 256 * i];
    if (t < 128) uL[t] = wsf[WS_U_F + t];
    else wL[t - 128] = wsf[WS_W_F + (t - 128)];
    __syncthreads();

    // hk-GEMM: hk = elu(dock @ wdm); wave w: m-tile mt=w, nt 0..7; K=16 (zero-padded)
    {
        int mt = w;
        short8 a;
        if (q < 2) a = *(const short8*)&dockRm[(mt * 16 + c) * 16 + q * 8];
        else a = short8{0, 0, 0, 0, 0, 0, 0, 0};
        float swp[4] = {0.f, 0.f, 0.f, 0.f};
        #pragma unroll
        for (int nt = 0; nt < 8; ++nt) {
            short8 bb;
            if (q < 2) bb = *(const short8*)&wdmTS[(nt * 16 + c) * 16 + q * 8];
            else bb = short8{0, 0, 0, 0, 0, 0, 0, 0};
            float4v acc = {0, 0, 0, 0};
            acc = __builtin_amdgcn_mfma_f32_16x16x32_bf16(a, bb, acc, 0, 0, 0);
            float wv = wL[nt * 16 + c];
            #pragma unroll
            for (int i = 0; i < 4; ++i) {
                float ev = elu_f(acc[i]);
                hkS[(mt * 16 + q * 4 + i) * 136 + nt * 16 + c] = f2bf(ev);
                swp[i] += ev * wv;
            }
        }
        #pragma unroll
        for (int i = 0; i < 4; ++i) {
            float sv = swp[i];
            sv += __shfl_xor(sv, 1, 16);
            sv += __shfl_xor(sv, 2, 16);
            sv += __shfl_xor(sv, 4, 16);
            sv += __shfl_xor(sv, 8, 16);
            if (c == 0) swL[mt * 16 + q * 4 + i] = sv;
        }
    }
    // su[n] = hd[n] . u  (8 partials per row)
    {
        int n = t >> 3, p = t & 7;
        float a = 0.f;
        #pragma unroll
        for (int kk = 0; kk < 16; kk += 2) {
            unsigned uu = *(const unsigned*)&hdS[n * 136 + p * 16 + kk];
            a += b2f((short)(uu & 0xffff)) * uL[p * 16 + kk]
               + b2f((short)(uu >> 16))   * uL[p * 16 + kk + 1];
        }
        a += __shfl_xor(a, 1, 8);
        a += __shfl_xor(a, 2, 8);
        a += __shfl_xor(a, 4, 8);
        if (p == 0) suL[n] = a;
    }
    __syncthreads();

    // t2-GEMM: t2 = hd @ M; wave w: mt=w&1, nt in [(w>>1)*4,+4); K=128
    {
        int mt = w & 1, ntb = (w >> 1) * 4;
        float4v acc[4] = { {0,0,0,0}, {0,0,0,0}, {0,0,0,0}, {0,0,0,0} };
        #pragma unroll
        for (int kq = 0; kq < 4; ++kq) {
            short8 a = *(const short8*)&hdS[(mt * 16 + c) * 136 + kq * 32 + q * 8];
            #pragma unroll
            for (int p = 0; p < 4; ++p) {
                short8 bb = *(const short8*)&MtS[((ntb + p) * 16 + c) * 128 + kq * 32 + q * 8];
                acc[p] = __builtin_amdgcn_mfma_f32_16x16x32_bf16(a, bb, acc[p], 0, 0, 0);
            }
        }
        __syncthreads();   // wdmTS dead; safe to overwrite with t2
        #pragma unroll
        for (int p = 0; p < 4; ++p)
            #pragma unroll
            for (int i = 0; i < 4; ++i)
                t2S[(mt * 16 + q * 4 + i) * 136 + (ntb + p) * 16 + c] = f2bf(acc[p][i]);
    }
    __syncthreads();

    // scores-GEMM: scores = t2 @ hk^T + su + sw + c0, mask, store
    {
        const float c0v = wsf[WS_C0_F];
        int ntd = w;
        float* lg = out_logits + (size_t)b * 2048;
        #pragma unroll
        for (int mt = 0; mt < 2; ++mt) {
            float4v acc = {0, 0, 0, 0};
            #pragma unroll
            for (int kq = 0; kq < 4; ++kq) {
                short8 a  = *(const short8*)&t2S[(mt * 16 + c) * 136 + kq * 32 + q * 8];
                short8 bb = *(const short8*)&hkS[(ntd * 16 + c) * 136 + kq * 32 + q * 8];
                acc = __builtin_amdgcn_mfma_f32_16x16x32_bf16(a, bb, acc, 0, 0, 0);
            }
            int col = ntd * 16 + c;
            float swv = swL[col];
            #pragma unroll
            for (int i = 0; i < 4; ++i) {
                int row = mt * 16 + q * 4 + i;
                float val = acc[i] + suL[row] + swv + c0v;
                bool keep = b2f(adjBf[row * 72 + col]) > 0.f;
                lg[row * 64 + col] = keep ? val : NEGC;
            }
        }
    }
}

extern "C" void kernel_launch(void* const* d_in, const int* in_sizes, int n_in,
                              void* d_out, int out_size, void* d_ws, size_t ws_size,
                              hipStream_t stream) {
    (void)in_sizes; (void)n_in; (void)out_size;
    const float* obs     = (const float*)d_in[0];
    const float* W_drone = (const float*)d_in[1];
    const float* W_dock  = (const float*)d_in[2];
    const float* a_src   = (const float*)d_in[3];
    const float* a_dst   = (const float*)d_in[4];
    const float* Wc1     = (const float*)d_in[5];
    const float* bc1     = (const float*)d_in[6];
    const float* Wc2     = (const float*)d_in[7];
    const float* bc2     = (const float*)d_in[8];
    const float* Wad     = (const float*)d_in[9];
    const float* bad     = (const float*)d_in[10];
    const float* Wak     = (const float*)d_in[11];
    const float* bak     = (const float*)d_in[12];
    float* out = (float*)d_out;
    float* wsf = (float*)d_ws;
    short* wss = (short*)d_ws;
    short* hdg = (short*)(out + 4096);     // HD bf16 stashed in logits region

    const bool big_ws = (ws_size >= WS_NEED_BYTES);

    setup_fold<<<dim3(18), dim3(256), 0, stream>>>(
        W_drone, W_dock, a_src, a_dst, Wad, Wak, bad, bak, wsf, wss);
    if (big_ws)
        setup_wc1<<<dim3(64), dim3(256), 0, stream>>>(
            Wc1, wss + WS_WC1H_S, wss + WS_WC1L_S);

    k1_attn_hd<<<dim3(4096), dim3(256), 0, stream>>>(obs, wsf, wss, hdg);

    if (big_ws)
        k2_critic2<<<dim3(256), dim3(256), 0, stream>>>(
            hdg, wss + WS_WC1H_S, wss + WS_WC1L_S, bc1, Wc2, bc2, out);
    else
        k2_critic<<<dim3(64), dim3(256), 0, stream>>>(hdg, Wc1, bc1, Wc2, bc2, out);

    k3_logits<<<dim3(4096), dim3(256), 0, stream>>>(obs, wsf, wss, out + 4096);
}

// Round 5
// 248.100 us; speedup vs baseline: 3.8161x; 1.0611x over previous
//
#include <hip/hip_runtime.h>
#include <math.h>

#define OBSD 3584
#define NEGC -9e15f

typedef short short8 __attribute__((ext_vector_type(8)));
typedef float float4v __attribute__((ext_vector_type(4)));

// ---- ws element offsets (shorts unless _F) ----
#define WS_MT_S   0        // short: Mt bf16 [128][128]  (Mt[i][r] = M[r][i])
#define WS_U_F    8192     // float: u[128]
#define WS_W_F    8320     // float: w[128]
#define WS_C0_F   8448     // float: c0
#define WS_AW_F   8452     // float: aw_dr[64], aw_dk[64]
#define WS_WDMT_S 17160    // short: wdmT bf16 [128][16]
#define WS_WFT_S  19208    // short: WflatT bf16 [128][64]
#define WS_WC1H_S 32768    // short: Wc1T hi bf16 [64][4096]
#define WS_WC1L_S 294912   // short: Wc1T lo bf16 [64][4096]
#define WS_HD_S   557056   // short: HD bf16 [4096][4096] (fused path only)
#define WS_NEED_BYTES  1114112ull
#define WS_NEED2_BYTES 34668544ull

__device__ __forceinline__ float elu_f(float x) {
    return x > 0.f ? x : (__expf(x) - 1.f);
}
__device__ __forceinline__ short f2bf(float f) {
    union { float f; unsigned u; } v; v.f = f;
    unsigned u = v.u;
    unsigned r = (u + 0x7fffu + ((u >> 16) & 1u)) >> 16;
    return (short)r;
}
__device__ __forceinline__ float b2f(short s) {
    union { unsigned u; float f; } v; v.u = ((unsigned)(unsigned short)s) << 16;
    return v.f;
}
__device__ __forceinline__ unsigned pk2(float a, float b) {
    return (unsigned)(unsigned short)f2bf(a) | ((unsigned)(unsigned short)f2bf(b) << 16);
}

// =============== K0: weight folding ===============
__global__ __launch_bounds__(256) void setup_fold(
    const float* __restrict__ W_drone, const float* __restrict__ W_dock,
    const float* __restrict__ a_src, const float* __restrict__ a_dst,
    const float* __restrict__ Wad, const float* __restrict__ Wak,
    const float* __restrict__ bad, const float* __restrict__ bak,
    float* __restrict__ wsf, short* __restrict__ wss)
{
    const int t = threadIdx.x, bi = blockIdx.x;
    if (bi < 16) {
        __shared__ float sa[32 * 132];
        __shared__ float sb[32 * 132];
        const int r0 = (bi >> 2) * 32, i0 = (bi & 3) * 32;
        #pragma unroll
        for (int qq = 0; qq < 4; ++qq) {
            int e = (t + 256 * qq) * 4;
            int r = e >> 7, cc = e & 127;
            *(float4*)&sa[r * 132 + cc] = *(const float4*)&Wad[(r0 + r) * 128 + cc];
            *(float4*)&sb[r * 132 + cc] = *(const float4*)&Wak[(i0 + r) * 128 + cc];
        }
        __syncthreads();
        int rr = (t >> 4) * 2, ii = (t & 15) * 2;
        float a00 = 0.f, a01 = 0.f, a10 = 0.f, a11 = 0.f;
        for (int c = 0; c < 128; ++c) {
            float x0 = sa[rr * 132 + c], x1 = sa[(rr + 1) * 132 + c];
            float y0 = sb[ii * 132 + c], y1 = sb[(ii + 1) * 132 + c];
            a00 += x0 * y0; a01 += x0 * y1; a10 += x1 * y0; a11 += x1 * y1;
        }
        wss[WS_MT_S + (i0 + ii) * 128 + (r0 + rr)]         = f2bf(a00);
        wss[WS_MT_S + (i0 + ii + 1) * 128 + (r0 + rr)]     = f2bf(a01);
        wss[WS_MT_S + (i0 + ii) * 128 + (r0 + rr + 1)]     = f2bf(a10);
        wss[WS_MT_S + (i0 + ii + 1) * 128 + (r0 + rr + 1)] = f2bf(a11);
    } else if (bi == 16) {
        if (t < 128) {
            float acc = 0.f;
            for (int c = 0; c < 128; ++c) acc += Wad[t * 128 + c] * bak[c];
            wsf[WS_U_F + t] = acc;
        } else {
            int j = t - 128;
            float acc = 0.f;
            for (int c = 0; c < 128; ++c) acc += Wak[j * 128 + c] * bad[c];
            wsf[WS_W_F + j] = acc;
        }
        if (t == 0) {
            float acc = 0.f;
            for (int c = 0; c < 128; ++c) acc += bad[c] * bak[c];
            wsf[WS_C0_F] = acc;
        }
    } else {
        if (t < 64) {
            int h = t >> 4, f = t & 15;
            const float* wrow = W_drone + h * 2048 + f * 128;
            const float* arow = a_src + h * 128;
            float acc = 0.f;
            for (int k = 0; k < 128; ++k) acc += wrow[k] * arow[k];
            wsf[WS_AW_F + t] = acc;
        } else if (t < 128) {
            int tt = t - 64;
            int h = tt >> 4, f = tt & 15;
            const float* wrow = W_dock + h * 2048 + f * 128;
            const float* arow = a_dst + h * 128;
            float acc = 0.f;
            for (int k = 0; k < 128; ++k) acc += wrow[k] * arow[k];
            wsf[WS_AW_F + 64 + tt] = acc;
        }
        for (int idx = t; idx < 2048; idx += 256) {
            int k2 = idx >> 4, f = idx & 15;
            float v = 0.25f * (W_dock[f * 128 + k2] + W_dock[2048 + f * 128 + k2]
                             + W_dock[4096 + f * 128 + k2] + W_dock[6144 + f * 128 + k2]);
            wss[WS_WDMT_S + k2 * 16 + f] = f2bf(v);
        }
        for (int idx = t; idx < 8192; idx += 256) {
            int k2 = idx >> 6, f64 = idx & 63;
            float v = W_dock[(f64 >> 4) * 2048 + (f64 & 15) * 128 + k2];
            wss[WS_WFT_S + k2 * 64 + f64] = f2bf(v);
        }
    }
}

// =============== K0b: Wc1 -> transposed bf16 hi/lo (coalesced via LDS tile) ===
__global__ __launch_bounds__(256) void setup_wc1(
    const float* __restrict__ Wc1,
    short* __restrict__ wc1h, short* __restrict__ wc1l)
{
    __shared__ float tile[64 * 68];
    const int t = threadIdx.x;
    const int k0 = blockIdx.x * 64;   // 64 blocks, k-tiles of 64
    {
        int r = t >> 2, c0 = (t & 3) * 16;   // coalesced: row r, 16 cols
        const float4* src = (const float4*)&Wc1[(size_t)(k0 + r) * 64 + c0];
        #pragma unroll
        for (int u = 0; u < 4; ++u)
            *(float4*)&tile[r * 68 + c0 + 4 * u] = src[u];
    }
    __syncthreads();
    {
        int col = t >> 2, kk0 = (t & 3) * 16;
        short hi[16], lo[16];
        #pragma unroll
        for (int j = 0; j < 16; ++j) {
            float v = tile[(kk0 + j) * 68 + col];
            hi[j] = f2bf(v);
            lo[j] = f2bf(v - b2f(hi[j]));
        }
        uint4* dh = (uint4*)(wc1h + (size_t)col * 4096 + k0 + kk0);
        uint4* dl = (uint4*)(wc1l + (size_t)col * 4096 + k0 + kk0);
        dh[0] = *(uint4*)&hi[0]; dh[1] = *(uint4*)&hi[8];
        dl[0] = *(uint4*)&lo[0]; dl[1] = *(uint4*)&lo[8];
    }
}

// =============== K13 fused: attention -> hd -> (HD to ws) -> logits ===========
// Phase A LDS:  sD@0, sK@1024, sAdj@3072, sAw@7680, sSrc@8192, sDst@8704,
//               sAt@9728, sT@28160, sHd@32768, sWf@41472  (.. 57856)
// Phase B LDS:  dockRm@0 (2048), [sAdj persists], suL@8192, swL@8320,
//               uL@8704, wL@9216, hkS@9728 (17408), wdmTS@28160 (4096),
//               t2S = sHd@32768, MtS@41472 (32768)  -> total 74240 B
__global__ __launch_bounds__(256, 2) void k13_fused(
    const float* __restrict__ obs,
    const float* __restrict__ wsf, const short* __restrict__ wss,
    short* __restrict__ hdg,            // HD in ws
    float* __restrict__ out_logits)
{
    __shared__ __align__(16) char sm[74240];
    short* sD     = (short*)(sm + 0);
    short* sK     = (short*)(sm + 1024);
    short* sAdj   = (short*)(sm + 3072);
    float* sAw    = (float*)(sm + 7680);
    float* sSrc   = (float*)(sm + 8192);
    float* sDst   = (float*)(sm + 8704);
    short* sAt    = (short*)(sm + 9728);
    short* sT     = (short*)(sm + 28160);
    short* sHd    = (short*)(sm + 32768);
    short* sWf    = (short*)(sm + 41472);
    // phase B aliases
    short* dockRm = (short*)(sm + 0);
    float* suL    = (float*)(sm + 8192);
    float* swL    = (float*)(sm + 8320);
    float* uL     = (float*)(sm + 8704);
    float* wL     = (float*)(sm + 9216);
    short* hkS    = (short*)(sm + 9728);
    short* wdmTS  = (short*)(sm + 28160);
    short* t2S    = (short*)(sm + 32768);
    short* MtS    = (short*)(sm + 41472);

    const int t = threadIdx.x;
    const int b = blockIdx.x;
    const float* obsrow = obs + (size_t)b * OBSD;
    const int L = t & 63, c = L & 15, q = L >> 4, w = t >> 6;

    // ---- P0: obs -> LDS (bf16)
    #pragma unroll
    for (int i = 0; i < 4; ++i) {
        int q4 = t + 256 * i;
        if (q4 < 896) {
            float4 v = ((const float4*)obsrow)[q4];
            int e0 = q4 * 4;
            if (e0 < 512) {
                int n = e0 >> 4, f0 = e0 & 15;
                sD[(f0 + 0) * 32 + n] = f2bf(v.x);
                sD[(f0 + 1) * 32 + n] = f2bf(v.y);
                sD[(f0 + 2) * 32 + n] = f2bf(v.z);
                sD[(f0 + 3) * 32 + n] = f2bf(v.w);
            } else if (e0 < 1536) {
                int e = e0 - 512;
                int m = e >> 4, f0 = e & 15;
                sK[(f0 + 0) * 64 + m] = f2bf(v.x);
                sK[(f0 + 1) * 64 + m] = f2bf(v.y);
                sK[(f0 + 2) * 64 + m] = f2bf(v.z);
                sK[(f0 + 3) * 64 + m] = f2bf(v.w);
            } else {
                int e = e0 - 1536;
                int n = e >> 6, m0 = e & 63;
                uint2 pkd = { pk2(v.x, v.y), pk2(v.z, v.w) };
                *(uint2*)&sAdj[n * 72 + m0] = pkd;
            }
        }
    }
    #pragma unroll
    for (int i = 0; i < 4; ++i)
        ((uint4*)sWf)[t + 256 * i] = ((const uint4*)(wss + WS_WFT_S))[t + 256 * i];
    if (t < 128) sAw[t] = wsf[WS_AW_F + t];
    __syncthreads();

    // src/dst
    if (t < 128) {
        int h = t >> 5, n = t & 31;
        float acc = 0.f;
        #pragma unroll
        for (int f = 0; f < 16; ++f) acc += b2f(sD[f * 32 + n]) * sAw[h * 16 + f];
        sSrc[h * 32 + n] = acc;
    }
    {
        int h = t >> 6, m = t & 63;
        float acc = 0.f;
        #pragma unroll
        for (int f = 0; f < 16; ++f) acc += b2f(sK[f * 64 + m]) * sAw[64 + h * 16 + f];
        sDst[h * 64 + m] = acc;
    }
    __syncthreads();

    // softmax: 2 lanes per row (128 rows)
    {
        int row = t >> 1, j = t & 1;
        int h = row >> 5, n = row & 31, m0 = j * 32;
        float sv = sSrc[h * 32 + n];
        float e32[32];
        float pmax = -INFINITY;
        #pragma unroll
        for (int mm = 0; mm < 32; ++mm) {
            int m = m0 + mm;
            float e = sv + sDst[h * 64 + m];
            e = e > 0.f ? e : 0.2f * e;
            e = (b2f(sAdj[n * 72 + m]) > 0.f) ? e : NEGC;
            e32[mm] = e;
            pmax = fmaxf(pmax, e);
        }
        pmax = fmaxf(pmax, __shfl_xor(pmax, 1, 2));
        float psum = 0.f;
        #pragma unroll
        for (int mm = 0; mm < 32; ++mm) { e32[mm] = __expf(e32[mm] - pmax); psum += e32[mm]; }
        psum += __shfl_xor(psum, 1, 2);
        float rinv = 1.f / psum;
        unsigned* ab = (unsigned*)sAt;
        int ub = (h * 2304 + n * 72 + m0) >> 1;
        #pragma unroll
        for (int mm = 0; mm < 32; mm += 2)
            ab[ub + (mm >> 1)] = pk2(e32[mm] * rinv, e32[mm + 1] * rinv);
    }
    __syncthreads();

    // T-GEMM
    {
        int h = w;
        float4v accT[2] = { {0,0,0,0}, {0,0,0,0} };
        #pragma unroll
        for (int mt = 0; mt < 2; ++mt)
            #pragma unroll
            for (int kq = 0; kq < 2; ++kq) {
                short8 a = *(const short8*)&sAt[h * 2304 + (mt * 16 + c) * 72 + kq * 32 + q * 8];
                short8 bb = *(const short8*)&sK[c * 64 + kq * 32 + q * 8];
                accT[mt] = __builtin_amdgcn_mfma_f32_16x16x32_bf16(a, bb, accT[mt], 0, 0, 0);
            }
        #pragma unroll
        for (int mt = 0; mt < 2; ++mt)
            #pragma unroll
            for (int i = 0; i < 4; ++i)
                sT[(mt * 16 + q * 4 + i) * 72 + h * 16 + c] = f2bf(accT[mt][i]);
    }
    __syncthreads();

    // hd-GEMM
    {
        int mt = w & 1, ntb = (w >> 1) * 4;
        float4v acc[4] = { {0,0,0,0}, {0,0,0,0}, {0,0,0,0}, {0,0,0,0} };
        #pragma unroll
        for (int kq = 0; kq < 2; ++kq) {
            short8 a = *(const short8*)&sT[(mt * 16 + c) * 72 + kq * 32 + q * 8];
            #pragma unroll
            for (int p = 0; p < 4; ++p) {
                short8 bb = *(const short8*)&sWf[((ntb + p) * 16 + c) * 64 + kq * 32 + q * 8];
                acc[p] = __builtin_amdgcn_mfma_f32_16x16x32_bf16(a, bb, acc[p], 0, 0, 0);
            }
        }
        #pragma unroll
        for (int p = 0; p < 4; ++p)
            #pragma unroll
            for (int i = 0; i < 4; ++i) {
                float v = elu_f(acc[p][i] * 0.25f);
                sHd[(mt * 16 + q * 4 + i) * 136 + (ntb + p) * 16 + c] = f2bf(v);
            }
    }
    __syncthreads();

    // ---- HD -> ws global (for critic), and phase-B staging
    {
        int n = t >> 3, k2 = (t & 7) * 16;
        uint4 x0 = *(const uint4*)&sHd[n * 136 + k2];
        uint4 x1 = *(const uint4*)&sHd[n * 136 + k2 + 8];
        uint4* dst = (uint4*)(hdg + (size_t)b * 4096 + n * 128 + k2);
        dst[0] = x0; dst[1] = x1;
    }
    {   // dock rows (row-major bf16) from obs
        float4 v = ((const float4*)obsrow)[128 + t];
        int m = t >> 2, f0 = (t & 3) * 4;
        uint2 pkd = { pk2(v.x, v.y), pk2(v.z, v.w) };
        *(uint2*)&dockRm[m * 16 + f0] = pkd;
    }
    ((uint4*)wdmTS)[t] = ((const uint4*)(wss + WS_WDMT_S))[t];
    #pragma unroll
    for (int i = 0; i < 8; ++i)
        ((uint4*)MtS)[t + 256 * i] = ((const uint4*)(wss + WS_MT_S))[t + 256 * i];
    if (t < 128) uL[t] = wsf[WS_U_F + t];
    else wL[t - 128] = wsf[WS_W_F + (t - 128)];
    __syncthreads();

    // hk-GEMM + sw
    {
        int mt = w;
        short8 a;
        if (q < 2) a = *(const short8*)&dockRm[(mt * 16 + c) * 16 + q * 8];
        else a = short8{0, 0, 0, 0, 0, 0, 0, 0};
        float swp[4] = {0.f, 0.f, 0.f, 0.f};
        #pragma unroll
        for (int nt = 0; nt < 8; ++nt) {
            short8 bb;
            if (q < 2) bb = *(const short8*)&wdmTS[(nt * 16 + c) * 16 + q * 8];
            else bb = short8{0, 0, 0, 0, 0, 0, 0, 0};
            float4v acc = {0, 0, 0, 0};
            acc = __builtin_amdgcn_mfma_f32_16x16x32_bf16(a, bb, acc, 0, 0, 0);
            float wv = wL[nt * 16 + c];
            #pragma unroll
            for (int i = 0; i < 4; ++i) {
                float ev = elu_f(acc[i]);
                hkS[(mt * 16 + q * 4 + i) * 136 + nt * 16 + c] = f2bf(ev);
                swp[i] += ev * wv;
            }
        }
        #pragma unroll
        for (int i = 0; i < 4; ++i) {
            float sv = swp[i];
            sv += __shfl_xor(sv, 1, 16);
            sv += __shfl_xor(sv, 2, 16);
            sv += __shfl_xor(sv, 4, 16);
            sv += __shfl_xor(sv, 8, 16);
            if (c == 0) swL[mt * 16 + q * 4 + i] = sv;
        }
    }
    // su[n] = hd[n] . u
    {
        int n = t >> 3, p = t & 7;
        float a = 0.f;
        #pragma unroll
        for (int kk = 0; kk < 16; kk += 2) {
            unsigned uu = *(const unsigned*)&sHd[n * 136 + p * 16 + kk];
            a += b2f((short)(uu & 0xffff)) * uL[p * 16 + kk]
               + b2f((short)(uu >> 16))   * uL[p * 16 + kk + 1];
        }
        a += __shfl_xor(a, 1, 8);
        a += __shfl_xor(a, 2, 8);
        a += __shfl_xor(a, 4, 8);
        if (p == 0) suL[n] = a;
    }
    __syncthreads();

    // t2-GEMM (reads sHd fully, then overwrites it with t2 after barrier)
    {
        int mt = w & 1, ntb = (w >> 1) * 4;
        float4v acc[4] = { {0,0,0,0}, {0,0,0,0}, {0,0,0,0}, {0,0,0,0} };
        #pragma unroll
        for (int kq = 0; kq < 4; ++kq) {
            short8 a = *(const short8*)&sHd[(mt * 16 + c) * 136 + kq * 32 + q * 8];
            #pragma unroll
            for (int p = 0; p < 4; ++p) {
                short8 bb = *(const short8*)&MtS[((ntb + p) * 16 + c) * 128 + kq * 32 + q * 8];
                acc[p] = __builtin_amdgcn_mfma_f32_16x16x32_bf16(a, bb, acc[p], 0, 0, 0);
            }
        }
        __syncthreads();
        #pragma unroll
        for (int p = 0; p < 4; ++p)
            #pragma unroll
            for (int i = 0; i < 4; ++i)
                t2S[(mt * 16 + q * 4 + i) * 136 + (ntb + p) * 16 + c] = f2bf(acc[p][i]);
    }
    __syncthreads();

    // scores = t2 @ hk^T + su + sw + c0, mask, store
    {
        const float c0v = wsf[WS_C0_F];
        int ntd = w;
        float* lg = out_logits + (size_t)b * 2048;
        #pragma unroll
        for (int mt = 0; mt < 2; ++mt) {
            float4v acc = {0, 0, 0, 0};
            #pragma unroll
            for (int kq = 0; kq < 4; ++kq) {
                short8 a  = *(const short8*)&t2S[(mt * 16 + c) * 136 + kq * 32 + q * 8];
                short8 bb = *(const short8*)&hkS[(ntd * 16 + c) * 136 + kq * 32 + q * 8];
                acc = __builtin_amdgcn_mfma_f32_16x16x32_bf16(a, bb, acc, 0, 0, 0);
            }
            int col = ntd * 16 + c;
            float swv = swL[col];
            #pragma unroll
            for (int i = 0; i < 4; ++i) {
                int row = mt * 16 + q * 4 + i;
                float val = acc[i] + suL[row] + swv + c0v;
                bool keep = b2f(sAdj[row * 72 + col]) > 0.f;
                lg[row * 64 + col] = keep ? val : NEGC;
            }
        }
    }
}

// =============== K1 (legacy): attention -> hd (HD stashed in logits region) ===
__global__ __launch_bounds__(256, 2) void k1_attn_hd(
    const float* __restrict__ obs,
    const float* __restrict__ wsf, const short* __restrict__ wss,
    short* __restrict__ hdg)
{
    __shared__ __align__(16) char sm[57856];
    short* sD   = (short*)(sm + 0);
    short* sK   = (short*)(sm + 1024);
    short* sAdj = (short*)(sm + 3072);
    float* sAw  = (float*)(sm + 7680);
    float* sSrc = (float*)(sm + 8192);
    float* sDst = (float*)(sm + 8704);
    short* sAt  = (short*)(sm + 9728);
    short* sT   = (short*)(sm + 28160);
    short* sHd  = (short*)(sm + 32768);
    short* sWf  = (short*)(sm + 41472);

    const int t = threadIdx.x;
    const int b = blockIdx.x;
    const float* obsrow = obs + (size_t)b * OBSD;
    const int L = t & 63, c = L & 15, q = L >> 4, w = t >> 6;

    #pragma unroll
    for (int i = 0; i < 4; ++i) {
        int q4 = t + 256 * i;
        if (q4 < 896) {
            float4 v = ((const float4*)obsrow)[q4];
            int e0 = q4 * 4;
            if (e0 < 512) {
                int n = e0 >> 4, f0 = e0 & 15;
                sD[(f0 + 0) * 32 + n] = f2bf(v.x);
                sD[(f0 + 1) * 32 + n] = f2bf(v.y);
                sD[(f0 + 2) * 32 + n] = f2bf(v.z);
                sD[(f0 + 3) * 32 + n] = f2bf(v.w);
            } else if (e0 < 1536) {
                int e = e0 - 512;
                int m = e >> 4, f0 = e & 15;
                sK[(f0 + 0) * 64 + m] = f2bf(v.x);
                sK[(f0 + 1) * 64 + m] = f2bf(v.y);
                sK[(f0 + 2) * 64 + m] = f2bf(v.z);
                sK[(f0 + 3) * 64 + m] = f2bf(v.w);
            } else {
                int e = e0 - 1536;
                int n = e >> 6, m0 = e & 63;
                uint2 pkd = { pk2(v.x, v.y), pk2(v.z, v.w) };
                *(uint2*)&sAdj[n * 72 + m0] = pkd;
            }
        }
    }
    #pragma unroll
    for (int i = 0; i < 4; ++i)
        ((uint4*)sWf)[t + 256 * i] = ((const uint4*)(wss + WS_WFT_S))[t + 256 * i];
    if (t < 128) sAw[t] = wsf[WS_AW_F + t];
    __syncthreads();

    if (t < 128) {
        int h = t >> 5, n = t & 31;
        float acc = 0.f;
        #pragma unroll
        for (int f = 0; f < 16; ++f) acc += b2f(sD[f * 32 + n]) * sAw[h * 16 + f];
        sSrc[h * 32 + n] = acc;
    }
    {
        int h = t >> 6, m = t & 63;
        float acc = 0.f;
        #pragma unroll
        for (int f = 0; f < 16; ++f) acc += b2f(sK[f * 64 + m]) * sAw[64 + h * 16 + f];
        sDst[h * 64 + m] = acc;
    }
    __syncthreads();

    {
        int row = t >> 1, j = t & 1;
        int h = row >> 5, n = row & 31, m0 = j * 32;
        float sv = sSrc[h * 32 + n];
        float e32[32];
        float pmax = -INFINITY;
        #pragma unroll
        for (int mm = 0; mm < 32; ++mm) {
            int m = m0 + mm;
            float e = sv + sDst[h * 64 + m];
            e = e > 0.f ? e : 0.2f * e;
            e = (b2f(sAdj[n * 72 + m]) > 0.f) ? e : NEGC;
            e32[mm] = e;
            pmax = fmaxf(pmax, e);
        }
        pmax = fmaxf(pmax, __shfl_xor(pmax, 1, 2));
        float psum = 0.f;
        #pragma unroll
        for (int mm = 0; mm < 32; ++mm) { e32[mm] = __expf(e32[mm] - pmax); psum += e32[mm]; }
        psum += __shfl_xor(psum, 1, 2);
        float rinv = 1.f / psum;
        unsigned* ab = (unsigned*)sAt;
        int ub = (h * 2304 + n * 72 + m0) >> 1;
        #pragma unroll
        for (int mm = 0; mm < 32; mm += 2)
            ab[ub + (mm >> 1)] = pk2(e32[mm] * rinv, e32[mm + 1] * rinv);
    }
    __syncthreads();

    {
        int h = w;
        float4v accT[2] = { {0,0,0,0}, {0,0,0,0} };
        #pragma unroll
        for (int mt = 0; mt < 2; ++mt)
            #pragma unroll
            for (int kq = 0; kq < 2; ++kq) {
                short8 a = *(const short8*)&sAt[h * 2304 + (mt * 16 + c) * 72 + kq * 32 + q * 8];
                short8 bb = *(const short8*)&sK[c * 64 + kq * 32 + q * 8];
                accT[mt] = __builtin_amdgcn_mfma_f32_16x16x32_bf16(a, bb, accT[mt], 0, 0, 0);
            }
        #pragma unroll
        for (int mt = 0; mt < 2; ++mt)
            #pragma unroll
            for (int i = 0; i < 4; ++i)
                sT[(mt * 16 + q * 4 + i) * 72 + h * 16 + c] = f2bf(accT[mt][i]);
    }
    __syncthreads();

    {
        int mt = w & 1, ntb = (w >> 1) * 4;
        float4v acc[4] = { {0,0,0,0}, {0,0,0,0}, {0,0,0,0}, {0,0,0,0} };
        #pragma unroll
        for (int kq = 0; kq < 2; ++kq) {
            short8 a = *(const short8*)&sT[(mt * 16 + c) * 72 + kq * 32 + q * 8];
            #pragma unroll
            for (int p = 0; p < 4; ++p) {
                short8 bb = *(const short8*)&sWf[((ntb + p) * 16 + c) * 64 + kq * 32 + q * 8];
                acc[p] = __builtin_amdgcn_mfma_f32_16x16x32_bf16(a, bb, acc[p], 0, 0, 0);
            }
        }
        #pragma unroll
        for (int p = 0; p < 4; ++p)
            #pragma unroll
            for (int i = 0; i < 4; ++i) {
                float v = elu_f(acc[p][i] * 0.25f);
                sHd[(mt * 16 + q * 4 + i) * 136 + (ntb + p) * 16 + c] = f2bf(v);
            }
    }
    __syncthreads();

    {
        int n = t >> 3, k2 = (t & 7) * 16;
        uint4 x0 = *(const uint4*)&sHd[n * 136 + k2];
        uint4 x1 = *(const uint4*)&sHd[n * 136 + k2 + 8];
        uint4* dst = (uint4*)(hdg + (size_t)b * 4096 + n * 128 + k2);
        dst[0] = x0; dst[1] = x1;
    }
}

// =============== K2 (fallback): critic GEMM, 64 blocks ===============
__global__ __launch_bounds__(256) void k2_critic(
    const short* __restrict__ hdg,
    const float* __restrict__ Wc1, const float* __restrict__ bc1,
    const float* __restrict__ Wc2, const float* __restrict__ bc2,
    float* __restrict__ out_values)
{
    __shared__ __align__(16) char sm[46592];
    short* As   = (short*)(sm + 0);
    float* Wst  = (float*)(sm + 9216);
    short* Bh   = (short*)(sm + 27648);
    short* Blo  = (short*)(sm + 36864);
    float* bc1L = (float*)(sm + 46080);
    float* wc2L = (float*)(sm + 46336);

    const int t = threadIdx.x;
    const int r0 = blockIdx.x * 64;
    const int L = t & 63, c = L & 15, q = L >> 4, w = t >> 6;

    if (t < 64) { bc1L[t] = bc1[t]; wc2L[t] = Wc2[t]; }

    float4v acc[4] = { {0,0,0,0}, {0,0,0,0}, {0,0,0,0}, {0,0,0,0} };

    for (int kc = 0; kc < 64; ++kc) {
        __syncthreads();
        {
            int r = t >> 2, kk0 = (t & 3) * 16;
            const uint4* src = (const uint4*)(hdg + (size_t)(r0 + r) * 4096 + kc * 64 + kk0);
            *(uint4*)&As[r * 72 + kk0]     = src[0];
            *(uint4*)&As[r * 72 + kk0 + 8] = src[1];
        }
        {
            int el = t >> 2, j0 = (t & 3) * 16;
            const float4* src = (const float4*)&Wc1[(size_t)(kc * 64 + el) * 64 + j0];
            #pragma unroll
            for (int u = 0; u < 4; ++u)
                *(float4*)&Wst[el * 72 + j0 + 4 * u] = src[u];
        }
        __syncthreads();
        {
            int j = t & 63, elb = (t >> 6) * 16;
            #pragma unroll
            for (int e = 0; e < 16; e += 2) {
                float v0 = Wst[(elb + e) * 72 + j];
                float v1 = Wst[(elb + e + 1) * 72 + j];
                short h0 = f2bf(v0), h1 = f2bf(v1);
                float l0 = v0 - b2f(h0), l1 = v1 - b2f(h1);
                *(unsigned*)&Bh[j * 72 + elb + e]  = (unsigned)(unsigned short)h0 | ((unsigned)(unsigned short)h1 << 16);
                *(unsigned*)&Blo[j * 72 + elb + e] = (unsigned)(unsigned short)f2bf(l0) | ((unsigned)(unsigned short)f2bf(l1) << 16);
            }
        }
        __syncthreads();
        #pragma unroll
        for (int kq = 0; kq < 2; ++kq) {
            short8 a = *(const short8*)&As[(w * 16 + c) * 72 + kq * 32 + q * 8];
            #pragma unroll
            for (int ct = 0; ct < 4; ++ct) {
                short8 bh = *(const short8*)&Bh[(ct * 16 + c) * 72 + kq * 32 + q * 8];
                short8 bl = *(const short8*)&Blo[(ct * 16 + c) * 72 + kq * 32 + q * 8];
                acc[ct] = __builtin_amdgcn_mfma_f32_16x16x32_bf16(a, bh, acc[ct], 0, 0, 0);
                acc[ct] = __builtin_amdgcn_mfma_f32_16x16x32_bf16(a, bl, acc[ct], 0, 0, 0);
            }
        }
    }
    float bc2v = bc2[0];
    #pragma unroll
    for (int i = 0; i < 4; ++i) {
        float sv = 0.f;
        #pragma unroll
        for (int ct = 0; ct < 4; ++ct) {
            float pre = acc[ct][i] + bc1L[ct * 16 + c];
            pre = fmaxf(pre, 0.f);
            sv += pre * wc2L[ct * 16 + c];
        }
        sv += __shfl_xor(sv, 1, 16);
        sv += __shfl_xor(sv, 2, 16);
        sv += __shfl_xor(sv, 4, 16);
        sv += __shfl_xor(sv, 8, 16);
        if (c == 0) out_values[r0 + w * 16 + q * 4 + i] = sv + bc2v;
    }
}

// =============== K2 (fast): critic GEMM, 256 blocks x 16 rows ===============
__global__ __launch_bounds__(256) void k2_critic2(
    const short* __restrict__ hdg,
    const short* __restrict__ wc1h, const short* __restrict__ wc1l,
    const float* __restrict__ bc1,
    const float* __restrict__ Wc2, const float* __restrict__ bc2,
    float* __restrict__ out_values)
{
    __shared__ __align__(16) char sm[39936];
    short* As   = (short*)(sm + 0);
    short* Bh   = (short*)(sm + 4352);
    short* Bl   = (short*)(sm + 21760);
    float* bc1L = (float*)(sm + 39168);
    float* wc2L = (float*)(sm + 39424);
    float* red  = (float*)(sm + 39680);

    const int t = threadIdx.x;
    const int r0 = blockIdx.x * 16;
    const int L = t & 63, c = L & 15, q = L >> 4, w = t >> 6;

    if (t < 64) { bc1L[t] = bc1[t]; wc2L[t] = Wc2[t]; }

    float4v acc = {0, 0, 0, 0};

    const int rA  = t >> 4,  kkA = (t & 15) * 8;
    const int colB = t >> 2, kbB = (t & 3) * 32;

    for (int it = 0; it < 32; ++it) {
        const int kc = it * 128;
        __syncthreads();
        *(uint4*)&As[rA * 136 + kkA] =
            *(const uint4*)(hdg + (size_t)(r0 + rA) * 4096 + kc + kkA);
        {
            const uint4* srcH = (const uint4*)(wc1h + (size_t)colB * 4096 + kc + kbB);
            const uint4* srcL = (const uint4*)(wc1l + (size_t)colB * 4096 + kc + kbB);
            #pragma unroll
            for (int u = 0; u < 4; ++u) {
                *(uint4*)&Bh[colB * 136 + kbB + 8 * u] = srcH[u];
                *(uint4*)&Bl[colB * 136 + kbB + 8 * u] = srcL[u];
            }
        }
        __syncthreads();
        #pragma unroll
        for (int kq = 0; kq < 4; ++kq) {
            short8 a  = *(const short8*)&As[c * 136 + kq * 32 + q * 8];
            short8 bh = *(const short8*)&Bh[(w * 16 + c) * 136 + kq * 32 + q * 8];
            short8 bl = *(const short8*)&Bl[(w * 16 + c) * 136 + kq * 32 + q * 8];
            acc = __builtin_amdgcn_mfma_f32_16x16x32_bf16(a, bh, acc, 0, 0, 0);
            acc = __builtin_amdgcn_mfma_f32_16x16x32_bf16(a, bl, acc, 0, 0, 0);
        }
    }
    #pragma unroll
    for (int i = 0; i < 4; ++i) {
        float pre = acc[i] + bc1L[w * 16 + c];
        pre = fmaxf(pre, 0.f);
        float sv = pre * wc2L[w * 16 + c];
        sv += __shfl_xor(sv, 1, 16);
        sv += __shfl_xor(sv, 2, 16);
        sv += __shfl_xor(sv, 4, 16);
        sv += __shfl_xor(sv, 8, 16);
        if (c == 0) red[w * 16 + q * 4 + i] = sv;
    }
    __syncthreads();
    if (t < 16) {
        float v = red[t] + red[16 + t] + red[32 + t] + red[48 + t] + bc2[0];
        out_values[r0 + t] = v;
    }
}

// =============== K3 (legacy): hk, t2, scores -> logits ===============
__global__ __launch_bounds__(256, 2) void k3_logits(
    const float* __restrict__ obs,
    const float* __restrict__ wsf, const short* __restrict__ wss,
    float* __restrict__ out_logits)
{
    __shared__ __align__(16) char sm[75648];
    short* dockRm = (short*)(sm + 0);
    short* adjBf  = (short*)(sm + 2048);
    short* hdS    = (short*)(sm + 6656);
    short* hkS    = (short*)(sm + 15360);
    short* wdmTS  = (short*)(sm + 32768);
    short* t2S    = (short*)(sm + 32768);
    float* suL    = (float*)(sm + 41472);
    float* swL    = (float*)(sm + 41600);
    float* uL     = (float*)(sm + 41856);
    float* wL     = (float*)(sm + 42368);
    short* MtS    = (short*)(sm + 42880);

    const int t = threadIdx.x;
    const int b = blockIdx.x;
    const float* obsrow = obs + (size_t)b * OBSD;
    short* hdg = (short*)out_logits;
    const int L = t & 63, c = L & 15, q = L >> 4, w = t >> 6;

    {
        int n = t >> 3, k2 = (t & 7) * 16;
        const uint4* src = (const uint4*)(hdg + (size_t)b * 4096 + n * 128 + k2);
        uint4 x0 = src[0], x1 = src[1];
        *(uint4*)&hdS[n * 136 + k2]     = x0;
        *(uint4*)&hdS[n * 136 + k2 + 8] = x1;
    }
    {
        float4 v = ((const float4*)obsrow)[128 + t];
        int m = t >> 2, f0 = (t & 3) * 4;
        uint2 pkd = { pk2(v.x, v.y), pk2(v.z, v.w) };
        *(uint2*)&dockRm[m * 16 + f0] = pkd;
    }
    #pragma unroll
    for (int i = 0; i < 2; ++i) {
        int q4 = 384 + t + 256 * i;
        if (q4 < 896) {
            float4 v = ((const float4*)obsrow)[q4];
            int e = q4 * 4 - 1536;
            int n = e >> 6, m0 = e & 63;
            uint2 pkd = { pk2(v.x, v.y), pk2(v.z, v.w) };
            *(uint2*)&adjBf[n * 72 + m0] = pkd;
        }
    }
    ((uint4*)wdmTS)[t] = ((const uint4*)(wss + WS_WDMT_S))[t];
    #pragma unroll
    for (int i = 0; i < 8; ++i)
        ((uint4*)MtS)[t + 256 * i] = ((const uint4*)(wss + WS_MT_S))[t + 256 * i];
    if (t < 128) uL[t] = wsf[WS_U_F + t];
    else wL[t - 128] = wsf[WS_W_F + (t - 128)];
    __syncthreads();

    {
        int mt = w;
        short8 a;
        if (q < 2) a = *(const short8*)&dockRm[(mt * 16 + c) * 16 + q * 8];
        else a = short8{0, 0, 0, 0, 0, 0, 0, 0};
        float swp[4] = {0.f, 0.f, 0.f, 0.f};
        #pragma unroll
        for (int nt = 0; nt < 8; ++nt) {
            short8 bb;
            if (q < 2) bb = *(const short8*)&wdmTS[(nt * 16 + c) * 16 + q * 8];
            else bb = short8{0, 0, 0, 0, 0, 0, 0, 0};
            float4v acc = {0, 0, 0, 0};
            acc = __builtin_amdgcn_mfma_f32_16x16x32_bf16(a, bb, acc, 0, 0, 0);
            float wv = wL[nt * 16 + c];
            #pragma unroll
            for (int i = 0; i < 4; ++i) {
                float ev = elu_f(acc[i]);
                hkS[(mt * 16 + q * 4 + i) * 136 + nt * 16 + c] = f2bf(ev);
                swp[i] += ev * wv;
            }
        }
        #pragma unroll
        for (int i = 0; i < 4; ++i) {
            float sv = swp[i];
            sv += __shfl_xor(sv, 1, 16);
            sv += __shfl_xor(sv, 2, 16);
            sv += __shfl_xor(sv, 4, 16);
            sv += __shfl_xor(sv, 8, 16);
            if (c == 0) swL[mt * 16 + q * 4 + i] = sv;
        }
    }
    {
        int n = t >> 3, p = t & 7;
        float a = 0.f;
        #pragma unroll
        for (int kk = 0; kk < 16; kk += 2) {
            unsigned uu = *(const unsigned*)&hdS[n * 136 + p * 16 + kk];
            a += b2f((short)(uu & 0xffff)) * uL[p * 16 + kk]
               + b2f((short)(uu >> 16))   * uL[p * 16 + kk + 1];
        }
        a += __shfl_xor(a, 1, 8);
        a += __shfl_xor(a, 2, 8);
        a += __shfl_xor(a, 4, 8);
        if (p == 0) suL[n] = a;
    }
    __syncthreads();

    {
        int mt = w & 1, ntb = (w >> 1) * 4;
        float4v acc[4] = { {0,0,0,0}, {0,0,0,0}, {0,0,0,0}, {0,0,0,0} };
        #pragma unroll
        for (int kq = 0; kq < 4; ++kq) {
            short8 a = *(const short8*)&hdS[(mt * 16 + c) * 136 + kq * 32 + q * 8];
            #pragma unroll
            for (int p = 0; p < 4; ++p) {
                short8 bb = *(const short8*)&MtS[((ntb + p) * 16 + c) * 128 + kq * 32 + q * 8];
                acc[p] = __builtin_amdgcn_mfma_f32_16x16x32_bf16(a, bb, acc[p], 0, 0, 0);
            }
        }
        __syncthreads();
        #pragma unroll
        for (int p = 0; p < 4; ++p)
            #pragma unroll
            for (int i = 0; i < 4; ++i)
                t2S[(mt * 16 + q * 4 + i) * 136 + (ntb + p) * 16 + c] = f2bf(acc[p][i]);
    }
    __syncthreads();

    {
        const float c0v = wsf[WS_C0_F];
        int ntd = w;
        float* lg = out_logits + (size_t)b * 2048;
        #pragma unroll
        for (int mt = 0; mt < 2; ++mt) {
            float4v acc = {0, 0, 0, 0};
            #pragma unroll
            for (int kq = 0; kq < 4; ++kq) {
                short8 a  = *(const short8*)&t2S[(mt * 16 + c) * 136 + kq * 32 + q * 8];
                short8 bb = *(const short8*)&hkS[(ntd * 16 + c) * 136 + kq * 32 + q * 8];
                acc = __builtin_amdgcn_mfma_f32_16x16x32_bf16(a, bb, acc, 0, 0, 0);
            }
            int col = ntd * 16 + c;
            float swv = swL[col];
            #pragma unroll
            for (int i = 0; i < 4; ++i) {
                int row = mt * 16 + q * 4 + i;
                float val = acc[i] + suL[row] + swv + c0v;
                bool keep = b2f(adjBf[row * 72 + col]) > 0.f;
                lg[row * 64 + col] = keep ? val : NEGC;
            }
        }
    }
}

extern "C" void kernel_launch(void* const* d_in, const int* in_sizes, int n_in,
                              void* d_out, int out_size, void* d_ws, size_t ws_size,
                              hipStream_t stream) {
    (void)in_sizes; (void)n_in; (void)out_size;
    const float* obs     = (const float*)d_in[0];
    const float* W_drone = (const float*)d_in[1];
    const float* W_dock  = (const float*)d_in[2];
    const float* a_src   = (const float*)d_in[3];
    const float* a_dst   = (const float*)d_in[4];
    const float* Wc1     = (const float*)d_in[5];
    const float* bc1     = (const float*)d_in[6];
    const float* Wc2     = (const float*)d_in[7];
    const float* bc2     = (const float*)d_in[8];
    const float* Wad     = (const float*)d_in[9];
    const float* bad     = (const float*)d_in[10];
    const float* Wak     = (const float*)d_in[11];
    const float* bak     = (const float*)d_in[12];
    float* out = (float*)d_out;
    float* wsf = (float*)d_ws;
    short* wss = (short*)d_ws;

    const bool ws_wc1 = (ws_size >= WS_NEED_BYTES);
    const bool ws_hd  = (ws_size >= WS_NEED2_BYTES);

    setup_fold<<<dim3(18), dim3(256), 0, stream>>>(
        W_drone, W_dock, a_src, a_dst, Wad, Wak, bad, bak, wsf, wss);
    if (ws_wc1)
        setup_wc1<<<dim3(64), dim3(256), 0, stream>>>(
            Wc1, wss + WS_WC1H_S, wss + WS_WC1L_S);

    if (ws_hd) {
        short* hdw = wss + WS_HD_S;
        k13_fused<<<dim3(4096), dim3(256), 0, stream>>>(
            obs, wsf, wss, hdw, out + 4096);
        k2_critic2<<<dim3(256), dim3(256), 0, stream>>>(
            hdw, wss + WS_WC1H_S, wss + WS_WC1L_S, bc1, Wc2, bc2, out);
    } else {
        short* hdg = (short*)(out + 4096);   // HD stashed in logits region
        k1_attn_hd<<<dim3(4096), dim3(256), 0, stream>>>(obs, wsf, wss, hdg);
        if (ws_wc1)
            k2_critic2<<<dim3(256), dim3(256), 0, stream>>>(
                hdg, wss + WS_WC1H_S, wss + WS_WC1L_S, bc1, Wc2, bc2, out);
        else
            k2_critic<<<dim3(64), dim3(256), 0, stream>>>(hdg, Wc1, bc1, Wc2, bc2, out);
        k3_logits<<<dim3(4096), dim3(256), 0, stream>>>(obs, wsf, wss, out + 4096);
    }
}